// Round 1
// baseline (4660.802 us; speedup 1.0000x reference)
//
#include <hip/hip_runtime.h>
#include <hip/hip_bf16.h>
#include <math.h>

#define C 256
#define NROWS (64*56*56)   // 200704
#define EPSV 0.001f

// ws layout (floats):
//  [0,256)                : channel sums
//  [256, 256+65536)       : S = sum x x^T
//  [65792, 65792+65536)   : Wg = gamma-folded L^{-1} (full 256x256, upper = 0)
//  [131328, 131584)       : bias = beta - gamma * (W m)

// ---------------- K1: per-channel sums ----------------
__global__ __launch_bounds__(256) void k_sums(const float* __restrict__ x,
                                              float* __restrict__ sums) {
    int c = threadIdx.x;
    float s = 0.f;
    for (int r = blockIdx.x; r < NROWS; r += gridDim.x)
        s += x[(size_t)r * C + c];
    atomicAdd(&sums[c], s);
}

// ---------------- K2: raw second moment S (lower-tri tiles) ----------------
__global__ __launch_bounds__(256) void k_cov(const float* __restrict__ x,
                                             float* __restrict__ S) {
    __shared__ __align__(16) float as[64][68];
    __shared__ __align__(16) float bs[64][68];
    int t = blockIdx.x;        // 0..9  lower-triangular tile pair
    int slice = blockIdx.y;    // 0..63
    int ti = 0;
    while (((ti + 1) * (ti + 2)) / 2 <= t) ++ti;
    int tj = t - (ti * (ti + 1)) / 2;
    int ci = ti * 64, cj = tj * 64;
    const int rows_per_slice = NROWS / 64;   // 3136
    int r0 = slice * rows_per_slice;
    int tid = threadIdx.x;
    int ia = (tid >> 4) * 4;   // 0..60
    int jb = (tid & 15) * 4;   // 0..60

    float acc[4][4];
#pragma unroll
    for (int a = 0; a < 4; ++a)
#pragma unroll
        for (int b = 0; b < 4; ++b) acc[a][b] = 0.f;

    for (int ch = 0; ch < rows_per_slice; ch += 64) {
        __syncthreads();
        for (int l = tid; l < 4096; l += 256) {
            int r = l >> 6, c = l & 63;
            const float* row = x + (size_t)(r0 + ch + r) * C;
            as[r][c] = row[ci + c];
            bs[r][c] = row[cj + c];
        }
        __syncthreads();
#pragma unroll 4
        for (int r = 0; r < 64; ++r) {
            float4 a4 = *(const float4*)&as[r][ia];
            float4 b4 = *(const float4*)&bs[r][jb];
            float av[4] = {a4.x, a4.y, a4.z, a4.w};
            float bv[4] = {b4.x, b4.y, b4.z, b4.w};
#pragma unroll
            for (int ii = 0; ii < 4; ++ii)
#pragma unroll
                for (int jj = 0; jj < 4; ++jj)
                    acc[ii][jj] += av[ii] * bv[jj];
        }
    }
#pragma unroll
    for (int ii = 0; ii < 4; ++ii)
#pragma unroll
        for (int jj = 0; jj < 4; ++jj)
            atomicAdd(&S[(ci + ia + ii) * C + (cj + jb + jj)], acc[ii][jj]);
}

// ---------------- K3: finalize cov + Cholesky + in-place inverse ----------------
__global__ __launch_bounds__(256) void k_chol(const float* __restrict__ S,
                                              const float* __restrict__ sums,
                                              const float* __restrict__ gamma,
                                              const float* __restrict__ beta,
                                              float* __restrict__ Wg,
                                              float* __restrict__ bias) {
    __shared__ float Lp[32896];   // packed lower triangle, 131.6 KB
    __shared__ float ms[256];
    int tid = threadIdx.x;
    ms[tid] = sums[tid] * (1.f / (float)NROWS);
    __syncthreads();

    const float scale = (1.f - EPSV) / ((float)NROWS - 1.f);
    for (int l = tid; l < 32896; l += 256) {
        int i = (int)((sqrtf(8.f * (float)l + 1.f) - 1.f) * 0.5f);
        while ((i * (i + 1)) / 2 > l) --i;
        while (((i + 1) * (i + 2)) / 2 <= l) ++i;
        int j = l - (i * (i + 1)) / 2;
        float v = (S[i * C + j] - (float)NROWS * ms[i] * ms[j]) * scale;
        if (i == j) v += EPSV;
        Lp[l] = v;
    }
    __syncthreads();

    // right-looking Cholesky on packed lower triangle
    for (int k = 0; k < C; ++k) {
        int trik = (k * (k + 1)) / 2;
        if (tid == 0) Lp[trik + k] = sqrtf(Lp[trik + k]);
        __syncthreads();
        float dinv = 1.f / Lp[trik + k];
        int i = k + 1 + tid;
        int trii = (i * (i + 1)) / 2;
        if (i < C) Lp[trii + k] *= dinv;
        __syncthreads();
        if (i < C) {
            float lik = Lp[trii + k];
            for (int j = k + 1; j <= i; ++j)
                Lp[trii + j] -= lik * Lp[(j * (j + 1)) / 2 + k];
        }
        __syncthreads();
    }

    // in-place inverse: row recurrence, row i of L read fully before overwrite
    for (int i = 0; i < C; ++i) {
        int trii = (i * (i + 1)) / 2;
        float dinv = 1.f / Lp[trii + i];
        int j = tid;
        float s = 0.f;
        if (j < i) {
            for (int k = j; k < i; ++k)
                s -= Lp[trii + k] * Lp[(k * (k + 1)) / 2 + j];
            s *= dinv;
        } else if (j == i) {
            s = dinv;
        }
        __syncthreads();
        if (j <= i) Lp[trii + j] = s;
        __syncthreads();
    }

    // bias and gamma-folded W
    {
        int trii = (tid * (tid + 1)) / 2;
        float wm = 0.f;
        for (int j = 0; j <= tid; ++j) wm += Lp[trii + j] * ms[j];
        bias[tid] = beta[tid] - gamma[tid] * wm;
    }
    __syncthreads();
    for (int l = tid; l < C * C; l += 256) {
        int i = l >> 8, j = l & 255;
        float w = (j <= i) ? Lp[(i * (i + 1)) / 2 + j] : 0.f;
        Wg[l] = gamma[i] * w;
    }
}

// ---------------- K4: out = x * Wg^T + bias ----------------
__global__ __launch_bounds__(256) void k_apply(const float* __restrict__ x,
                                               const float* __restrict__ Wg,
                                               const float* __restrict__ bias,
                                               float* __restrict__ out) {
    __shared__ __align__(16) float xsT[32][68];    // [k][row]
    __shared__ __align__(16) float wsT[32][260];   // [k][col]
    int tid = threadIdx.x;
    int wave = tid >> 6, lane = tid & 63;
    int r0 = blockIdx.x * 64;

    float4 acc4[16];
#pragma unroll
    for (int m = 0; m < 16; ++m) acc4[m] = make_float4(0.f, 0.f, 0.f, 0.f);

    for (int kc = 0; kc < C; kc += 32) {
        __syncthreads();
        for (int l = tid; l < 2048; l += 256) {
            int r = l >> 5, k = l & 31;
            xsT[k][r] = x[(size_t)(r0 + r) * C + kc + k];
        }
        for (int l = tid; l < 8192; l += 256) {
            int col = l >> 5, k = l & 31;
            wsT[k][col] = Wg[col * C + kc + k];
        }
        __syncthreads();
#pragma unroll 8
        for (int k = 0; k < 32; ++k) {
            float4 b4 = *(const float4*)&wsT[k][lane * 4];
#pragma unroll
            for (int mm = 0; mm < 4; ++mm) {
                float4 a4 = *(const float4*)&xsT[k][wave * 16 + mm * 4];
                float av[4] = {a4.x, a4.y, a4.z, a4.w};
#pragma unroll
                for (int t = 0; t < 4; ++t) {
                    acc4[mm * 4 + t].x += av[t] * b4.x;
                    acc4[mm * 4 + t].y += av[t] * b4.y;
                    acc4[mm * 4 + t].z += av[t] * b4.z;
                    acc4[mm * 4 + t].w += av[t] * b4.w;
                }
            }
        }
    }

    float4 bias4 = *(const float4*)&bias[lane * 4];
#pragma unroll
    for (int m = 0; m < 16; ++m) {
        int r = r0 + wave * 16 + m;
        float4 v;
        v.x = acc4[m].x + bias4.x;
        v.y = acc4[m].y + bias4.y;
        v.z = acc4[m].z + bias4.z;
        v.w = acc4[m].w + bias4.w;
        *(float4*)&out[(size_t)r * C + lane * 4] = v;
    }
}

extern "C" void kernel_launch(void* const* d_in, const int* in_sizes, int n_in,
                              void* d_out, int out_size, void* d_ws, size_t ws_size,
                              hipStream_t stream) {
    const float* x     = (const float*)d_in[0];
    const float* gamma = (const float*)d_in[1];
    const float* beta  = (const float*)d_in[2];
    float* out  = (float*)d_out;
    float* ws   = (float*)d_ws;
    float* sums = ws;                    // 256
    float* S    = ws + 256;              // 65536
    float* Wg   = ws + 256 + 65536;      // 65536
    float* bias = ws + 256 + 2 * 65536;  // 256

    hipMemsetAsync(ws, 0, (256 + 65536) * sizeof(float), stream);
    hipLaunchKernelGGL(k_sums, dim3(512), dim3(256), 0, stream, x, sums);
    hipLaunchKernelGGL(k_cov, dim3(10, 64), dim3(256), 0, stream, x, S);
    hipLaunchKernelGGL(k_chol, dim3(1), dim3(256), 0, stream, S, sums, gamma, beta, Wg, bias);
    hipLaunchKernelGGL(k_apply, dim3(3136), dim3(256), 0, stream, x, Wg, bias, out);
}

// Round 2
// 1567.414 us; speedup vs baseline: 2.9736x; 2.9736x over previous
//
#include <hip/hip_runtime.h>
#include <hip/hip_bf16.h>
#include <math.h>

#define C 256
#define NROWS (64*56*56)   // 200704
#define EPSV 0.001f
#define TRI(i) (((i)*((i)+1))>>1)

// ws layout (floats):
//  [0,256)                : channel sums
//  [256, 256+65536)       : S = sum x x^T
//  [65792, 65792+65536)   : Wg = gamma-folded L^{-1} (full 256x256, upper = 0)
//  [131328, 131584)       : bias = beta - gamma * (W m)

// ---------------- K1: per-channel sums ----------------
__global__ __launch_bounds__(256) void k_sums(const float* __restrict__ x,
                                              float* __restrict__ sums) {
    int c = threadIdx.x;
    float s = 0.f;
    for (int r = blockIdx.x; r < NROWS; r += gridDim.x)
        s += x[(size_t)r * C + c];
    atomicAdd(&sums[c], s);
}

// ---------------- K2: raw second moment S (lower-tri tiles) ----------------
__global__ __launch_bounds__(256) void k_cov(const float* __restrict__ x,
                                             float* __restrict__ S) {
    __shared__ __align__(16) float as[64][68];
    __shared__ __align__(16) float bs[64][68];
    int t = blockIdx.x;        // 0..9  lower-triangular tile pair
    int slice = blockIdx.y;    // 0..63
    int ti = 0;
    while (((ti + 1) * (ti + 2)) / 2 <= t) ++ti;
    int tj = t - (ti * (ti + 1)) / 2;
    int ci = ti * 64, cj = tj * 64;
    const int rows_per_slice = NROWS / 64;   // 3136
    int r0 = slice * rows_per_slice;
    int tid = threadIdx.x;
    int ia = (tid >> 4) * 4;   // 0..60
    int jb = (tid & 15) * 4;   // 0..60

    float acc[4][4];
#pragma unroll
    for (int a = 0; a < 4; ++a)
#pragma unroll
        for (int b = 0; b < 4; ++b) acc[a][b] = 0.f;

    for (int ch = 0; ch < rows_per_slice; ch += 64) {
        __syncthreads();
        for (int l = tid; l < 4096; l += 256) {
            int r = l >> 6, c = l & 63;
            const float* row = x + (size_t)(r0 + ch + r) * C;
            as[r][c] = row[ci + c];
            bs[r][c] = row[cj + c];
        }
        __syncthreads();
#pragma unroll 4
        for (int r = 0; r < 64; ++r) {
            float4 a4 = *(const float4*)&as[r][ia];
            float4 b4 = *(const float4*)&bs[r][jb];
            float av[4] = {a4.x, a4.y, a4.z, a4.w};
            float bv[4] = {b4.x, b4.y, b4.z, b4.w};
#pragma unroll
            for (int ii = 0; ii < 4; ++ii)
#pragma unroll
                for (int jj = 0; jj < 4; ++jj)
                    acc[ii][jj] += av[ii] * bv[jj];
        }
    }
#pragma unroll
    for (int ii = 0; ii < 4; ++ii)
#pragma unroll
        for (int jj = 0; jj < 4; ++jj)
            atomicAdd(&S[(ci + ia + ii) * C + (cj + jb + jj)], acc[ii][jj]);
}

// ---------------- K3: finalize cov + blocked Cholesky + blocked inverse ----------------
__global__ __launch_bounds__(256) void k_chol(const float* __restrict__ S,
                                              const float* __restrict__ sums,
                                              const float* __restrict__ gamma,
                                              const float* __restrict__ beta,
                                              float* __restrict__ Wg,
                                              float* __restrict__ bias) {
    __shared__ float Lp[32896];      // packed lower triangle (131.6 KB)
    __shared__ float ms[256];
    __shared__ float Dtmp[32][33];   // diag-block scratch / T staging
    __shared__ float col32[32];
    int tid = threadIdx.x;
    ms[tid] = sums[tid] * (1.f / (float)NROWS);
    __syncthreads();

    const float scale = (1.f - EPSV) / ((float)NROWS - 1.f);
    for (int l = tid; l < 32896; l += 256) {
        int i = (int)((sqrtf(8.f * (float)l + 1.f) - 1.f) * 0.5f);
        while (TRI(i) > l) --i;
        while (TRI(i + 1) <= l) ++i;
        int j = l - TRI(i);
        float v = (S[i * C + j] - (float)NROWS * ms[i] * ms[j]) * scale;
        if (i == j) v += EPSV;
        Lp[l] = v;
    }
    __syncthreads();

    int r2 = (tid >> 4) * 2;     // row pair within 32x32 block
    int c2 = (tid & 15) * 2;     // col pair within 32x32 block

    // ---------- blocked Cholesky (panel = 32) ----------
    for (int kb = 0; kb < 8; ++kb) {
        int k0 = kb * 32;

        // copy diag block (lower) into Dtmp
        for (int l = tid; l < 1024; l += 256) {
            int i = l >> 5, j = l & 31;
            if (j <= i) Dtmp[i][j] = Lp[TRI(k0 + i) + k0 + j];
        }
        __syncthreads();

        // factor Dtmp in place: 2 barriers per step
        for (int k = 0; k < 32; ++k) {
            float d = sqrtf(Dtmp[k][k]);
            float dinv = 1.f / d;
            for (int l = tid; l < 1024; l += 256) {
                int i = l >> 5, j = l & 31;
                if (i >= j && j >= k) {
                    if (j == k) {
                        col32[i] = (i == k) ? d : Dtmp[i][k] * dinv;
                    } else {
                        Dtmp[i][j] -= (Dtmp[i][k] * dinv) * (Dtmp[j][k] * dinv);
                    }
                }
            }
            __syncthreads();
            if (tid >= k && tid < 32) Dtmp[tid][k] = col32[tid];
            __syncthreads();
        }

        // invert Dtmp (lower-tri) -> write Dinv into packed diag block (replaces L11)
        if (tid < 32) {
            int c = tid;
            Lp[TRI(k0 + c) + k0 + c] = 1.f / Dtmp[c][c];
            for (int i = c + 1; i < 32; ++i) {
                float s = 0.f;
                for (int k = c; k < i; ++k)
                    s += Dtmp[i][k] * Lp[TRI(k0 + k) + k0 + c];
                Lp[TRI(k0 + i) + k0 + c] = -s / Dtmp[i][i];
            }
        }
        __syncthreads();

        // panel solve: L21 = A21 * Dinv^T, row-owned (no barriers inside)
        int m = 256 - k0 - 32;
        if (tid < m) {
            int r = k0 + 32 + tid;
            int base = TRI(r) + k0;
            float a[32];
#pragma unroll
            for (int k = 0; k < 32; ++k) a[k] = Lp[base + k];
#pragma unroll
            for (int cc = 0; cc < 32; ++cc) {
                int db = TRI(k0 + cc) + k0;
                float s = 0.f;
#pragma unroll
                for (int k = 0; k <= cc; ++k) s += a[k] * Lp[db + k];
                Lp[base + cc] = s;
            }
        }
        __syncthreads();

        // trailing update: A22 -= L21 L21^T, block pairs, 2x2 reg tiles, no barriers inside
        for (int ib = kb + 1; ib < 8; ++ib) {
            for (int jbb = kb + 1; jbb <= ib; ++jbb) {
                int gi0 = ib * 32 + r2, gj0 = jbb * 32 + c2;
                int bi0 = TRI(gi0) + k0;
                int bi1 = bi0 + gi0 + 1;          // TRI(gi0+1)+k0
                int bj0 = TRI(gj0) + k0;
                int bj1 = bj0 + gj0 + 1;
                float a00 = 0, a01 = 0, a10 = 0, a11 = 0;
#pragma unroll 8
                for (int k = 0; k < 32; ++k) {
                    float ai0 = Lp[bi0 + k], ai1 = Lp[bi1 + k];
                    float aj0 = Lp[bj0 + k], aj1 = Lp[bj1 + k];
                    a00 += ai0 * aj0; a01 += ai0 * aj1;
                    a10 += ai1 * aj0; a11 += ai1 * aj1;
                }
                int wb0 = TRI(gi0) + gj0;
                int wb1 = wb0 + gi0 + 1;
                if (gj0     <= gi0    ) Lp[wb0]     -= a00;
                if (gj0 + 1 <= gi0    ) Lp[wb0 + 1] -= a01;
                if (gj0     <= gi0 + 1) Lp[wb1]     -= a10;
                if (gj0 + 1 <= gi0 + 1) Lp[wb1 + 1] -= a11;
            }
        }
        __syncthreads();
    }

    // ---------- blocked inverse: W[i][j] = -Dinv_i * sum_{k=j..i-1} L[i][k] W[k][j] ----------
    for (int ib = 1; ib < 8; ++ib) {
        for (int jbb = 0; jbb < ib; ++jbb) {
            float t00 = 0, t01 = 0, t10 = 0, t11 = 0;
            for (int kb2 = jbb; kb2 < ib; ++kb2) {
                bool dg = (kb2 == jbb);
                int rbase = kb2 * 32;
                int bw = TRI(rbase) + jbb * 32 + c2;
                int bi0 = TRI(ib * 32 + r2) + rbase;
                int bi1 = bi0 + ib * 32 + r2 + 1;
#pragma unroll 4
                for (int q = 0; q < 32; ++q) {
                    float w0 = Lp[bw], w1 = Lp[bw + 1];
                    if (dg) {
                        if (q < c2)     w0 = 0.f;
                        if (q < c2 + 1) w1 = 0.f;
                    }
                    float l0 = Lp[bi0 + q], l1 = Lp[bi1 + q];
                    t00 += l0 * w0; t01 += l0 * w1;
                    t10 += l1 * w0; t11 += l1 * w1;
                    bw += rbase + q + 1;
                }
            }
            __syncthreads();   // protect Dtmp overwrite (prev iter's reads done)
            Dtmp[r2][c2] = t00;     Dtmp[r2][c2 + 1] = t01;
            Dtmp[r2 + 1][c2] = t10; Dtmp[r2 + 1][c2 + 1] = t11;
            __syncthreads();
            // W = -Dinv_i * T
            int dr0 = TRI(ib * 32 + r2) + ib * 32;
            int dr1 = dr0 + ib * 32 + r2 + 1;
            float w00 = 0, w01 = 0, w10 = 0, w11 = 0;
            for (int q = 0; q <= r2 + 1; ++q) {
                float d0 = (q <= r2) ? Lp[dr0 + q] : 0.f;
                float d1 = Lp[dr1 + q];
                float tq0 = Dtmp[q][c2], tq1 = Dtmp[q][c2 + 1];
                w00 += d0 * tq0; w01 += d0 * tq1;
                w10 += d1 * tq0; w11 += d1 * tq1;
            }
            int ob0 = TRI(ib * 32 + r2) + jbb * 32 + c2;
            int ob1 = ob0 + ib * 32 + r2 + 1;
            Lp[ob0] = -w00; Lp[ob0 + 1] = -w01;
            Lp[ob1] = -w10; Lp[ob1 + 1] = -w11;
        }
    }
    __syncthreads();

    // bias and gamma-folded W
    {
        int trii = TRI(tid);
        float wm = 0.f;
        for (int j = 0; j <= tid; ++j) wm += Lp[trii + j] * ms[j];
        bias[tid] = beta[tid] - gamma[tid] * wm;
    }
    __syncthreads();
    for (int l = tid; l < C * C; l += 256) {
        int i = l >> 8, j = l & 255;
        float w = (j <= i) ? Lp[TRI(i) + j] : 0.f;
        Wg[l] = gamma[i] * w;
    }
}

// ---------------- K4: out = x * Wg^T + bias ----------------
__global__ __launch_bounds__(256) void k_apply(const float* __restrict__ x,
                                               const float* __restrict__ Wg,
                                               const float* __restrict__ bias,
                                               float* __restrict__ out) {
    __shared__ __align__(16) float xsT[32][68];    // [k][row]
    __shared__ __align__(16) float wsT[32][260];   // [k][col]
    int tid = threadIdx.x;
    int wave = tid >> 6, lane = tid & 63;
    int r0 = blockIdx.x * 64;

    float4 acc4[16];
#pragma unroll
    for (int m = 0; m < 16; ++m) acc4[m] = make_float4(0.f, 0.f, 0.f, 0.f);

    for (int kc = 0; kc < C; kc += 32) {
        __syncthreads();
        for (int l = tid; l < 2048; l += 256) {
            int r = l >> 5, k = l & 31;
            xsT[k][r] = x[(size_t)(r0 + r) * C + kc + k];
        }
        for (int l = tid; l < 8192; l += 256) {
            int col = l >> 5, k = l & 31;
            wsT[k][col] = Wg[col * C + kc + k];
        }
        __syncthreads();
#pragma unroll 8
        for (int k = 0; k < 32; ++k) {
            float4 b4 = *(const float4*)&wsT[k][lane * 4];
#pragma unroll
            for (int mm = 0; mm < 4; ++mm) {
                float4 a4 = *(const float4*)&xsT[k][wave * 16 + mm * 4];
                float av[4] = {a4.x, a4.y, a4.z, a4.w};
#pragma unroll
                for (int t = 0; t < 4; ++t) {
                    acc4[mm * 4 + t].x += av[t] * b4.x;
                    acc4[mm * 4 + t].y += av[t] * b4.y;
                    acc4[mm * 4 + t].z += av[t] * b4.z;
                    acc4[mm * 4 + t].w += av[t] * b4.w;
                }
            }
        }
    }

    float4 bias4 = *(const float4*)&bias[lane * 4];
#pragma unroll
    for (int m = 0; m < 16; ++m) {
        int r = r0 + wave * 16 + m;
        float4 v;
        v.x = acc4[m].x + bias4.x;
        v.y = acc4[m].y + bias4.y;
        v.z = acc4[m].z + bias4.z;
        v.w = acc4[m].w + bias4.w;
        *(float4*)&out[(size_t)r * C + lane * 4] = v;
    }
}

extern "C" void kernel_launch(void* const* d_in, const int* in_sizes, int n_in,
                              void* d_out, int out_size, void* d_ws, size_t ws_size,
                              hipStream_t stream) {
    const float* x     = (const float*)d_in[0];
    const float* gamma = (const float*)d_in[1];
    const float* beta  = (const float*)d_in[2];
    float* out  = (float*)d_out;
    float* ws   = (float*)d_ws;
    float* sums = ws;                    // 256
    float* S    = ws + 256;              // 65536
    float* Wg   = ws + 256 + 65536;      // 65536
    float* bias = ws + 256 + 2 * 65536;  // 256

    hipMemsetAsync(ws, 0, (256 + 65536) * sizeof(float), stream);
    hipLaunchKernelGGL(k_sums, dim3(512), dim3(256), 0, stream, x, sums);
    hipLaunchKernelGGL(k_cov, dim3(10, 64), dim3(256), 0, stream, x, S);
    hipLaunchKernelGGL(k_chol, dim3(1), dim3(256), 0, stream, S, sums, gamma, beta, Wg, bias);
    hipLaunchKernelGGL(k_apply, dim3(3136), dim3(256), 0, stream, x, Wg, bias, out);
}

// Round 3
// 1421.838 us; speedup vs baseline: 3.2780x; 1.1024x over previous
//
#include <hip/hip_runtime.h>
#include <hip/hip_bf16.h>
#include <math.h>

#define C 256
#define NROWS (64*56*56)   // 200704
#define EPSV 0.001f
#define TRI(i) (((i)*((i)+1))>>1)

// ws layout (floats):
//  [0,256)                : channel sums
//  [256, 256+65536)       : S = sum x x^T
//  [65792, 65792+65536)   : Wg = gamma-folded L^{-1} (full 256x256, upper = 0)
//  [131328, 131584)       : bias = beta - gamma * (W m)

// ---------------- K1: per-channel sums ----------------
__global__ __launch_bounds__(256) void k_sums(const float* __restrict__ x,
                                              float* __restrict__ sums) {
    int c = threadIdx.x;
    float s = 0.f;
    for (int r = blockIdx.x; r < NROWS; r += gridDim.x)
        s += x[(size_t)r * C + c];
    atomicAdd(&sums[c], s);
}

// ---------------- K2: raw second moment S (lower-tri tiles) ----------------
__global__ __launch_bounds__(256) void k_cov(const float* __restrict__ x,
                                             float* __restrict__ S) {
    __shared__ __align__(16) float as[64][68];
    __shared__ __align__(16) float bs[64][68];
    int t = blockIdx.x;        // 0..9  lower-triangular tile pair
    int slice = blockIdx.y;    // 0..63
    int ti = 0;
    while (((ti + 1) * (ti + 2)) / 2 <= t) ++ti;
    int tj = t - (ti * (ti + 1)) / 2;
    int ci = ti * 64, cj = tj * 64;
    const int rows_per_slice = NROWS / 64;   // 3136
    int r0 = slice * rows_per_slice;
    int tid = threadIdx.x;
    int ia = (tid >> 4) * 4;   // 0..60
    int jb = (tid & 15) * 4;   // 0..60

    float acc[4][4];
#pragma unroll
    for (int a = 0; a < 4; ++a)
#pragma unroll
        for (int b = 0; b < 4; ++b) acc[a][b] = 0.f;

    for (int ch = 0; ch < rows_per_slice; ch += 64) {
        __syncthreads();
        for (int l = tid; l < 4096; l += 256) {
            int r = l >> 6, c = l & 63;
            const float* row = x + (size_t)(r0 + ch + r) * C;
            as[r][c] = row[ci + c];
            bs[r][c] = row[cj + c];
        }
        __syncthreads();
#pragma unroll 4
        for (int r = 0; r < 64; ++r) {
            float4 a4 = *(const float4*)&as[r][ia];
            float4 b4 = *(const float4*)&bs[r][jb];
            float av[4] = {a4.x, a4.y, a4.z, a4.w};
            float bv[4] = {b4.x, b4.y, b4.z, b4.w};
#pragma unroll
            for (int ii = 0; ii < 4; ++ii)
#pragma unroll
                for (int jj = 0; jj < 4; ++jj)
                    acc[ii][jj] += av[ii] * bv[jj];
        }
    }
#pragma unroll
    for (int ii = 0; ii < 4; ++ii)
#pragma unroll
        for (int jj = 0; jj < 4; ++jj)
            atomicAdd(&S[(ci + ia + ii) * C + (cj + jb + jj)], acc[ii][jj]);
}

// ---------------- K3: finalize cov + blocked Cholesky + blocked inverse ----------------
// 1024 threads (16 waves), 4x4 register tiles, 1 barrier per diag-factor step.
__global__ __launch_bounds__(1024) void k_chol(const float* __restrict__ S,
                                               const float* __restrict__ sums,
                                               const float* __restrict__ gamma,
                                               const float* __restrict__ beta,
                                               float* __restrict__ Wg,
                                               float* __restrict__ bias) {
    __shared__ float Lp[32896];        // packed lower triangle (131.6 KB)
    __shared__ float ms[256];
    __shared__ float Dtmp[7][32][33];  // diag scratch [0] + T staging (29.6 KB)
    __shared__ float col32[32];        // per-step dinv
    __shared__ float ds_[32];          // per-step d
    int tid = threadIdx.x;
    if (tid < 256) ms[tid] = sums[tid] * (1.f / (float)NROWS);
    __syncthreads();

    const float scale = (1.f - EPSV) / ((float)NROWS - 1.f);
    for (int l = tid; l < 32896; l += 1024) {
        int i = (int)((sqrtf(8.f * (float)l + 1.f) - 1.f) * 0.5f);
        while (TRI(i) > l) --i;
        while (TRI(i + 1) <= l) ++i;
        int j = l - TRI(i);
        float v = (S[i * C + j] - (float)NROWS * ms[i] * ms[j]) * scale;
        if (i == j) v += EPSV;
        Lp[l] = v;
    }
    __syncthreads();

    int di = tid >> 5, dj = tid & 31;       // 32x32 map (diag factor)
    int slot = tid >> 6, sub = tid & 63;    // 16 slots of 64 threads
    int r4 = (sub >> 3) * 4, c4 = (sub & 7) * 4;  // 4x4 tile coords

    // ---------- blocked Cholesky (panel = 32) ----------
    for (int kb = 0; kb < 8; ++kb) {
        int k0 = kb * 32;

        // copy diag block (lower) into Dtmp[0] — one element per thread
        if (dj <= di) Dtmp[0][di][dj] = Lp[TRI(k0 + di) + k0 + dj];
        __syncthreads();

        // factor: raw columns kept, scale on the fly; 1 barrier/step
        for (int k = 0; k < 32; ++k) {
            float dkk = Dtmp[0][k][k];
            float d = sqrtf(dkk);
            float dinv = 1.f / d;
            if (tid == k) { col32[k] = dinv; ds_[k] = d; }
            if (di >= dj && dj > k)
                Dtmp[0][di][dj] -= (Dtmp[0][di][k] * dinv) * (Dtmp[0][dj][k] * dinv);
            __syncthreads();
        }
        // finalize L: scale columns, set diagonal
        if (di > dj)       Dtmp[0][di][dj] *= col32[dj];
        else if (di == dj) Dtmp[0][di][di] = ds_[di];
        __syncthreads();

        // invert Dtmp[0] (lower-tri) -> Dinv into packed diag block
        if (tid < 32) {
            int cc = tid;
            Lp[TRI(k0 + cc) + k0 + cc] = 1.f / Dtmp[0][cc][cc];
            for (int i2 = cc + 1; i2 < 32; ++i2) {
                float s = 0.f;
                for (int k = cc; k < i2; ++k)
                    s += Dtmp[0][i2][k] * Lp[TRI(k0 + k) + k0 + cc];
                Lp[TRI(k0 + i2) + k0 + cc] = -s / Dtmp[0][i2][i2];
            }
        }
        __syncthreads();

        // panel solve: L21 = A21 * Dinv^T; row x 4-col-group split
        {
            int m = 224 - k0;
            int r = tid >> 2, g = tid & 3;
            bool act = (r < m);
            int base = act ? (TRI(k0 + 32 + r) + k0) : 0;
            float a[32];
            if (act) {
#pragma unroll
                for (int k = 0; k < 32; ++k) a[k] = Lp[base + k];
            }
            __syncthreads();
            if (act) {
                for (int cc = g * 8; cc < g * 8 + 8; ++cc) {
                    int db = TRI(k0 + cc) + k0;
                    float s = 0.f;
                    for (int k = 0; k <= cc; ++k) s += a[k] * Lp[db + k];
                    Lp[base + cc] = s;
                }
            }
            __syncthreads();
        }

        // trailing update: A22 -= L21 L21^T, 16 block-pairs in flight, 4x4 tiles
        {
            int na = 7 - kb;
            int npairs = TRI(na);
            for (int p = slot; p < npairs; p += 16) {
                int a2 = 0;
                while (TRI(a2 + 1) <= p) ++a2;
                int b2 = p - TRI(a2);
                int ib = kb + 1 + a2, jbb = kb + 1 + b2;
                int gi = ib * 32 + r4, gj = jbb * 32 + c4;
                int bi0 = TRI(gi) + k0, bi1 = bi0 + gi + 1, bi2 = bi1 + gi + 2, bi3 = bi2 + gi + 3;
                int bj0 = TRI(gj) + k0, bj1 = bj0 + gj + 1, bj2 = bj1 + gj + 2, bj3 = bj2 + gj + 3;
                float acc[4][4];
#pragma unroll
                for (int ii = 0; ii < 4; ++ii)
#pragma unroll
                    for (int jj = 0; jj < 4; ++jj) acc[ii][jj] = 0.f;
#pragma unroll 8
                for (int k = 0; k < 32; ++k) {
                    float ai0 = Lp[bi0 + k], ai1 = Lp[bi1 + k], ai2 = Lp[bi2 + k], ai3 = Lp[bi3 + k];
                    float aj0 = Lp[bj0 + k], aj1 = Lp[bj1 + k], aj2 = Lp[bj2 + k], aj3 = Lp[bj3 + k];
                    acc[0][0] += ai0 * aj0; acc[0][1] += ai0 * aj1; acc[0][2] += ai0 * aj2; acc[0][3] += ai0 * aj3;
                    acc[1][0] += ai1 * aj0; acc[1][1] += ai1 * aj1; acc[1][2] += ai1 * aj2; acc[1][3] += ai1 * aj3;
                    acc[2][0] += ai2 * aj0; acc[2][1] += ai2 * aj1; acc[2][2] += ai2 * aj2; acc[2][3] += ai2 * aj3;
                    acc[3][0] += ai3 * aj0; acc[3][1] += ai3 * aj1; acc[3][2] += ai3 * aj2; acc[3][3] += ai3 * aj3;
                }
#pragma unroll
                for (int rr = 0; rr < 4; ++rr) {
                    int grow = gi + rr;
                    int wb = TRI(grow) + gj;
#pragma unroll
                    for (int cc2 = 0; cc2 < 4; ++cc2)
                        if (gj + cc2 <= grow) Lp[wb + cc2] -= acc[rr][cc2];
                }
            }
            __syncthreads();
        }
    }

    // ---------- blocked inverse: all jbb of block-row ib concurrently ----------
    for (int ib = 1; ib < 8; ++ib) {
        bool act = (slot < ib);
        int jbb = slot;
        float t[4][4];
#pragma unroll
        for (int ii = 0; ii < 4; ++ii)
#pragma unroll
            for (int jj = 0; jj < 4; ++jj) t[ii][jj] = 0.f;
        if (act) {
            for (int kb2 = jbb; kb2 < ib; ++kb2) {
                int rbase = kb2 * 32;
                int bw = TRI(rbase) + jbb * 32 + c4;
                int gi = ib * 32 + r4;
                int bi0 = TRI(gi) + rbase, bi1 = bi0 + gi + 1, bi2 = bi1 + gi + 2, bi3 = bi2 + gi + 3;
                bool dg = (kb2 == jbb);
#pragma unroll 4
                for (int q = 0; q < 32; ++q) {
                    float w0 = Lp[bw], w1 = Lp[bw + 1], w2 = Lp[bw + 2], w3 = Lp[bw + 3];
                    if (dg) {
                        if (q < c4)     w0 = 0.f;
                        if (q < c4 + 1) w1 = 0.f;
                        if (q < c4 + 2) w2 = 0.f;
                        if (q < c4 + 3) w3 = 0.f;
                    }
                    float l0 = Lp[bi0 + q], l1 = Lp[bi1 + q], l2 = Lp[bi2 + q], l3 = Lp[bi3 + q];
                    t[0][0] += l0 * w0; t[0][1] += l0 * w1; t[0][2] += l0 * w2; t[0][3] += l0 * w3;
                    t[1][0] += l1 * w0; t[1][1] += l1 * w1; t[1][2] += l1 * w2; t[1][3] += l1 * w3;
                    t[2][0] += l2 * w0; t[2][1] += l2 * w1; t[2][2] += l2 * w2; t[2][3] += l2 * w3;
                    t[3][0] += l3 * w0; t[3][1] += l3 * w1; t[3][2] += l3 * w2; t[3][3] += l3 * w3;
                    bw += rbase + q + 1;
                }
            }
        }
        __syncthreads();
        if (act) {
#pragma unroll
            for (int rr = 0; rr < 4; ++rr)
#pragma unroll
                for (int cc2 = 0; cc2 < 4; ++cc2)
                    Dtmp[slot][r4 + rr][c4 + cc2] = t[rr][cc2];
        }
        __syncthreads();
        if (act) {
            int gi = ib * 32 + r4;
            int dr0 = TRI(gi) + ib * 32, dr1 = dr0 + gi + 1, dr2 = dr1 + gi + 2, dr3 = dr2 + gi + 3;
            float w[4][4];
#pragma unroll
            for (int ii = 0; ii < 4; ++ii)
#pragma unroll
                for (int jj = 0; jj < 4; ++jj) w[ii][jj] = 0.f;
            for (int q = 0; q <= r4 + 3; ++q) {
                float d0 = (q <= r4)     ? Lp[dr0 + q] : 0.f;
                float d1 = (q <= r4 + 1) ? Lp[dr1 + q] : 0.f;
                float d2 = (q <= r4 + 2) ? Lp[dr2 + q] : 0.f;
                float d3 = Lp[dr3 + q];
                float t0 = Dtmp[slot][q][c4], t1 = Dtmp[slot][q][c4 + 1];
                float t2 = Dtmp[slot][q][c4 + 2], t3 = Dtmp[slot][q][c4 + 3];
                w[0][0] += d0 * t0; w[0][1] += d0 * t1; w[0][2] += d0 * t2; w[0][3] += d0 * t3;
                w[1][0] += d1 * t0; w[1][1] += d1 * t1; w[1][2] += d1 * t2; w[1][3] += d1 * t3;
                w[2][0] += d2 * t0; w[2][1] += d2 * t1; w[2][2] += d2 * t2; w[2][3] += d2 * t3;
                w[3][0] += d3 * t0; w[3][1] += d3 * t1; w[3][2] += d3 * t2; w[3][3] += d3 * t3;
            }
#pragma unroll
            for (int rr = 0; rr < 4; ++rr) {
                int ob = TRI(gi + rr) + jbb * 32 + c4;
#pragma unroll
                for (int cc2 = 0; cc2 < 4; ++cc2)
                    Lp[ob + cc2] = -w[rr][cc2];
            }
        }
        __syncthreads();
    }

    // bias and gamma-folded W
    if (tid < 256) {
        int trii = TRI(tid);
        float wm = 0.f;
        for (int j = 0; j <= tid; ++j) wm += Lp[trii + j] * ms[j];
        bias[tid] = beta[tid] - gamma[tid] * wm;
    }
    __syncthreads();
    for (int l = tid; l < C * C; l += 1024) {
        int i = l >> 8, j = l & 255;
        float w = (j <= i) ? Lp[TRI(i) + j] : 0.f;
        Wg[l] = gamma[i] * w;
    }
}

// ---------------- K4: out = x * Wg^T + bias ----------------
__global__ __launch_bounds__(256) void k_apply(const float* __restrict__ x,
                                               const float* __restrict__ Wg,
                                               const float* __restrict__ bias,
                                               float* __restrict__ out) {
    __shared__ __align__(16) float xsT[32][68];    // [k][row]
    __shared__ __align__(16) float wsT[32][260];   // [k][col]
    int tid = threadIdx.x;
    int wave = tid >> 6, lane = tid & 63;
    int r0 = blockIdx.x * 64;

    float4 acc4[16];
#pragma unroll
    for (int m = 0; m < 16; ++m) acc4[m] = make_float4(0.f, 0.f, 0.f, 0.f);

    for (int kc = 0; kc < C; kc += 32) {
        __syncthreads();
        for (int l = tid; l < 2048; l += 256) {
            int r = l >> 5, k = l & 31;
            xsT[k][r] = x[(size_t)(r0 + r) * C + kc + k];
        }
        for (int l = tid; l < 8192; l += 256) {
            int col = l >> 5, k = l & 31;
            wsT[k][col] = Wg[col * C + kc + k];
        }
        __syncthreads();
#pragma unroll 8
        for (int k = 0; k < 32; ++k) {
            float4 b4 = *(const float4*)&wsT[k][lane * 4];
#pragma unroll
            for (int mm = 0; mm < 4; ++mm) {
                float4 a4 = *(const float4*)&xsT[k][wave * 16 + mm * 4];
                float av[4] = {a4.x, a4.y, a4.z, a4.w};
#pragma unroll
                for (int t = 0; t < 4; ++t) {
                    acc4[mm * 4 + t].x += av[t] * b4.x;
                    acc4[mm * 4 + t].y += av[t] * b4.y;
                    acc4[mm * 4 + t].z += av[t] * b4.z;
                    acc4[mm * 4 + t].w += av[t] * b4.w;
                }
            }
        }
    }

    float4 bias4 = *(const float4*)&bias[lane * 4];
#pragma unroll
    for (int m = 0; m < 16; ++m) {
        int r = r0 + wave * 16 + m;
        float4 v;
        v.x = acc4[m].x + bias4.x;
        v.y = acc4[m].y + bias4.y;
        v.z = acc4[m].z + bias4.z;
        v.w = acc4[m].w + bias4.w;
        *(float4*)&out[(size_t)r * C + lane * 4] = v;
    }
}

extern "C" void kernel_launch(void* const* d_in, const int* in_sizes, int n_in,
                              void* d_out, int out_size, void* d_ws, size_t ws_size,
                              hipStream_t stream) {
    const float* x     = (const float*)d_in[0];
    const float* gamma = (const float*)d_in[1];
    const float* beta  = (const float*)d_in[2];
    float* out  = (float*)d_out;
    float* ws   = (float*)d_ws;
    float* sums = ws;                    // 256
    float* S    = ws + 256;              // 65536
    float* Wg   = ws + 256 + 65536;      // 65536
    float* bias = ws + 256 + 2 * 65536;  // 256

    hipMemsetAsync(ws, 0, (256 + 65536) * sizeof(float), stream);
    hipLaunchKernelGGL(k_sums, dim3(512), dim3(256), 0, stream, x, sums);
    hipLaunchKernelGGL(k_cov, dim3(10, 64), dim3(256), 0, stream, x, S);
    hipLaunchKernelGGL(k_chol, dim3(1), dim3(1024), 0, stream, S, sums, gamma, beta, Wg, bias);
    hipLaunchKernelGGL(k_apply, dim3(3136), dim3(256), 0, stream, x, Wg, bias, out);
}

// Round 4
// 1346.660 us; speedup vs baseline: 3.4610x; 1.0558x over previous
//
#include <hip/hip_runtime.h>
#include <hip/hip_bf16.h>
#include <math.h>

#define C 256
#define NROWS (64*56*56)   // 200704
#define EPSV 0.001f
#define TRI(i) (((i)*((i)+1))>>1)

// padded packed-lower-triangle layout: row i starts at PAD(i), rows rounded to 4 floats
__device__ __forceinline__ int PAD(int i) {
    int a = i >> 2, b = i & 3;
    return ((a + 1) * (2 * a + b)) << 2;
}
// total size: PAD(255)+256 = 33024+256 = 33280 floats

// ws layout (floats):
//  [0,256)                : channel sums
//  [256, 256+65536)       : S = sum x x^T
//  [65792, 65792+65536)   : Wg
//  [131328, 131584)       : bias

// ---------------- K2: raw second moment S + fused channel sums ----------------
__global__ __launch_bounds__(256) void k_cov(const float* __restrict__ x,
                                             float* __restrict__ S,
                                             float* __restrict__ sums) {
    __shared__ __align__(16) float as[64][68];
    __shared__ __align__(16) float bs[64][68];
    int t = blockIdx.x;        // 0..9  lower-triangular tile pair
    int slice = blockIdx.y;    // 0..63
    int ti = 0;
    while (((ti + 1) * (ti + 2)) / 2 <= t) ++ti;
    int tj = t - (ti * (ti + 1)) / 2;
    int ci = ti * 64, cj = tj * 64;
    bool isdiag = (ti == tj);
    const int rows_per_slice = NROWS / 64;   // 3136
    int r0 = slice * rows_per_slice;
    int tid = threadIdx.x;
    int ia = (tid >> 4) * 4;
    int jb = (tid & 15) * 4;

    float acc[4][4];
#pragma unroll
    for (int a = 0; a < 4; ++a)
#pragma unroll
        for (int b = 0; b < 4; ++b) acc[a][b] = 0.f;
    float colsum = 0.f;

    for (int ch = 0; ch < rows_per_slice; ch += 64) {
        __syncthreads();
        for (int l = tid; l < 4096; l += 256) {
            int r = l >> 6, c = l & 63;
            const float* row = x + (size_t)(r0 + ch + r) * C;
            float av = row[ci + c];
            as[r][c] = av;
            bs[r][c] = row[cj + c];
            if (isdiag) colsum += av;
        }
        __syncthreads();
#pragma unroll 4
        for (int r = 0; r < 64; ++r) {
            float4 a4 = *(const float4*)&as[r][ia];
            float4 b4 = *(const float4*)&bs[r][jb];
            float av[4] = {a4.x, a4.y, a4.z, a4.w};
            float bv[4] = {b4.x, b4.y, b4.z, b4.w};
#pragma unroll
            for (int ii = 0; ii < 4; ++ii)
#pragma unroll
                for (int jj = 0; jj < 4; ++jj)
                    acc[ii][jj] += av[ii] * bv[jj];
        }
    }
#pragma unroll
    for (int ii = 0; ii < 4; ++ii)
#pragma unroll
        for (int jj = 0; jj < 4; ++jj)
            atomicAdd(&S[(ci + ia + ii) * C + (cj + jb + jj)], acc[ii][jj]);
    if (isdiag) atomicAdd(&sums[ci + (tid & 63)], colsum);
}

// ---------------- k_chol helpers (templated NR keeps register indexing static) ----------------
template<int NR>
__device__ __forceinline__ void trail_unit(float* __restrict__ Lp, int k0,
                                           int ib2, int jb2, int r4, int c4) {
    int gj = jb2 * 32 + c4;
    int brow[4], arow[NR];
#pragma unroll
    for (int cc = 0; cc < 4; ++cc) brow[cc] = PAD(gj + cc) + k0;
#pragma unroll
    for (int rr = 0; rr < NR; ++rr) arow[rr] = PAD(ib2 * 32 + r4 + rr) + k0;
    float acc[NR][4];
#pragma unroll
    for (int rr = 0; rr < NR; ++rr)
#pragma unroll
        for (int cc = 0; cc < 4; ++cc) acc[rr][cc] = 0.f;
#pragma unroll
    for (int k4 = 0; k4 < 32; k4 += 4) {
        float4 b0 = *(const float4*)&Lp[brow[0] + k4];
        float4 b1 = *(const float4*)&Lp[brow[1] + k4];
        float4 b2 = *(const float4*)&Lp[brow[2] + k4];
        float4 b3 = *(const float4*)&Lp[brow[3] + k4];
#pragma unroll
        for (int rr = 0; rr < NR; ++rr) {
            float4 av = *(const float4*)&Lp[arow[rr] + k4];
            acc[rr][0] += av.x*b0.x + av.y*b0.y + av.z*b0.z + av.w*b0.w;
            acc[rr][1] += av.x*b1.x + av.y*b1.y + av.z*b1.z + av.w*b1.w;
            acc[rr][2] += av.x*b2.x + av.y*b2.y + av.z*b2.z + av.w*b2.w;
            acc[rr][3] += av.x*b3.x + av.y*b3.y + av.z*b3.z + av.w*b3.w;
        }
    }
    if (ib2 != jb2) {
#pragma unroll
        for (int rr = 0; rr < NR; ++rr) {
            int wb = PAD(ib2 * 32 + r4 + rr) + gj;
            float4 o = *(const float4*)&Lp[wb];
            o.x -= acc[rr][0]; o.y -= acc[rr][1]; o.z -= acc[rr][2]; o.w -= acc[rr][3];
            *(float4*)&Lp[wb] = o;
        }
    } else {
#pragma unroll
        for (int rr = 0; rr < NR; ++rr) {
            int rloc = r4 + rr;
            int wb = PAD(ib2 * 32 + rloc) + gj;
#pragma unroll
            for (int cc = 0; cc < 4; ++cc)
                if (c4 + cc <= rloc) Lp[wb + cc] -= acc[rr][cc];
        }
    }
}

template<int NR>
__device__ __forceinline__ void inv_t_unit(float* __restrict__ Lp, float* __restrict__ Tst,
                                           int ib2, int jb2, int r4, int c4) {
    float t[NR][4];
#pragma unroll
    for (int rr = 0; rr < NR; ++rr)
#pragma unroll
        for (int cc = 0; cc < 4; ++cc) t[rr][cc] = 0.f;
    int lrow[NR];
#pragma unroll
    for (int rr = 0; rr < NR; ++rr) lrow[rr] = PAD(ib2 * 32 + r4 + rr);
    int wcol = jb2 * 32 + c4;
    for (int kb2 = jb2 + 1; kb2 < ib2; ++kb2) {
#pragma unroll
        for (int q4 = 0; q4 < 32; q4 += 4) {
            float4 w0 = *(const float4*)&Lp[PAD(kb2*32 + q4)     + wcol];
            float4 w1 = *(const float4*)&Lp[PAD(kb2*32 + q4 + 1) + wcol];
            float4 w2 = *(const float4*)&Lp[PAD(kb2*32 + q4 + 2) + wcol];
            float4 w3 = *(const float4*)&Lp[PAD(kb2*32 + q4 + 3) + wcol];
#pragma unroll
            for (int rr = 0; rr < NR; ++rr) {
                float4 lv = *(const float4*)&Lp[lrow[rr] + kb2*32 + q4];
                t[rr][0] += lv.x*w0.x + lv.y*w1.x + lv.z*w2.x + lv.w*w3.x;
                t[rr][1] += lv.x*w0.y + lv.y*w1.y + lv.z*w2.y + lv.w*w3.y;
                t[rr][2] += lv.x*w0.z + lv.y*w1.z + lv.z*w2.z + lv.w*w3.z;
                t[rr][3] += lv.x*w0.w + lv.y*w1.w + lv.z*w2.w + lv.w*w3.w;
            }
        }
    }
    // diag block term: W[jb2][jb2] = Dinv (lower-tri), masked scalar
    int db = jb2 * 32;
    for (int q = c4; q < 32; ++q) {
        int wrow = PAD(db + q) + db;
        float wv[4];
#pragma unroll
        for (int cc = 0; cc < 4; ++cc)
            wv[cc] = (q >= c4 + cc) ? Lp[wrow + c4 + cc] : 0.f;
#pragma unroll
        for (int rr = 0; rr < NR; ++rr) {
            float lv = Lp[lrow[rr] + db + q];
            t[rr][0] += lv * wv[0]; t[rr][1] += lv * wv[1];
            t[rr][2] += lv * wv[2]; t[rr][3] += lv * wv[3];
        }
    }
#pragma unroll
    for (int rr = 0; rr < NR; ++rr) {
        float4 res; res.x = t[rr][0]; res.y = t[rr][1]; res.z = t[rr][2]; res.w = t[rr][3];
        *(float4*)&Tst[(r4 + rr) * 36 + c4] = res;
    }
}

template<int NR>
__device__ __forceinline__ void inv_w_unit(float* __restrict__ Lp, const float* __restrict__ Tst,
                                           int ib2, int jb2, int r4, int c4) {
#pragma unroll
    for (int rr = 0; rr < NR; ++rr) {
        int r = r4 + rr;
        int drow = PAD(ib2 * 32 + r) + ib2 * 32;
        float w0 = 0, w1 = 0, w2 = 0, w3 = 0;
        int qfull = (r + 1) & ~3;
        for (int q4 = 0; q4 < qfull; q4 += 4) {
            float4 dv = *(const float4*)&Lp[drow + q4];
            float4 t0 = *(const float4*)&Tst[(q4 + 0) * 36 + c4];
            float4 t1 = *(const float4*)&Tst[(q4 + 1) * 36 + c4];
            float4 t2 = *(const float4*)&Tst[(q4 + 2) * 36 + c4];
            float4 t3 = *(const float4*)&Tst[(q4 + 3) * 36 + c4];
            w0 += dv.x*t0.x + dv.y*t1.x + dv.z*t2.x + dv.w*t3.x;
            w1 += dv.x*t0.y + dv.y*t1.y + dv.z*t2.y + dv.w*t3.y;
            w2 += dv.x*t0.z + dv.y*t1.z + dv.z*t2.z + dv.w*t3.z;
            w3 += dv.x*t0.w + dv.y*t1.w + dv.z*t2.w + dv.w*t3.w;
        }
        for (int q = qfull; q <= r; ++q) {
            float dv = Lp[drow + q];
            float4 tq = *(const float4*)&Tst[q * 36 + c4];
            w0 += dv*tq.x; w1 += dv*tq.y; w2 += dv*tq.z; w3 += dv*tq.w;
        }
        float4 res; res.x = -w0; res.y = -w1; res.z = -w2; res.w = -w3;
        *(float4*)&Lp[PAD(ib2 * 32 + r) + jb2 * 32 + c4] = res;
    }
}

// ---------------- K3: finalize cov + blocked Cholesky + blocked inverse ----------------
__global__ __launch_bounds__(512) void k_chol(const float* __restrict__ S,
                                              const float* __restrict__ sums,
                                              const float* __restrict__ gamma,
                                              const float* __restrict__ beta,
                                              float* __restrict__ Wg,
                                              float* __restrict__ bias) {
    __shared__ __align__(16) float Lp[33280];       // 133.1 KB padded triangle
    __shared__ __align__(16) float ms[256];
    __shared__ __align__(16) float Dtmp[4][32][36]; // [0]=diag scratch, [3]=DinvSq, all=T staging
    int tid = threadIdx.x;
    if (tid < 256) ms[tid] = sums[tid] * (1.f / (float)NROWS);
    __syncthreads();

    const float scale = (1.f - EPSV) / ((float)NROWS - 1.f);
    for (int l = tid; l < 32896; l += 512) {
        int i = (int)((sqrtf(8.f * (float)l + 1.f) - 1.f) * 0.5f);
        while (TRI(i) > l) --i;
        while (TRI(i + 1) <= l) ++i;
        int j = l - TRI(i);
        float v = (S[i * C + j] - (float)NROWS * ms[i] * ms[j]) * scale;
        if (i == j) v += EPSV;
        Lp[PAD(i) + j] = v;
    }
    __syncthreads();

    int slot = tid >> 6, sub = tid & 63;
    int c4 = (sub & 7) * 4;
    float* D0 = &Dtmp[0][0][0];   // stride 36
    float* DS = &Dtmp[3][0][0];   // DinvSq, stride 36

    // wave-0 element assignment for diag factor (static register indexing)
    int ei[9], ej[9];
#pragma unroll
    for (int e = 0; e < 9; ++e) {
        int idx = tid + e * 64;
        if (tid < 64 && idx < 528) {
            int i = (int)((sqrtf(8.f * (float)idx + 1.f) - 1.f) * 0.5f);
            while (TRI(i) > idx) --i;
            while (TRI(i + 1) <= idx) ++i;
            ei[e] = i; ej[e] = idx - TRI(i);
        } else { ei[e] = -1; ej[e] = 0; }
    }

    // ---------- blocked Cholesky (panel = 32) ----------
    for (int kb = 0; kb < 8; ++kb) {
        int k0 = kb * 32;

        if (tid < 64) {
            // copy diag block into D0
#pragma unroll
            for (int e = 0; e < 9; ++e)
                if (ei[e] >= 0) D0[ei[e] * 36 + ej[e]] = Lp[PAD(k0 + ei[e]) + k0 + ej[e]];
            __threadfence_block();
            // raw-column right-looking factor (wave-synchronous, no barriers)
            for (int k = 0; k < 32; ++k) {
                float rinv = 1.f / D0[k * 36 + k];
#pragma unroll
                for (int e = 0; e < 9; ++e) {
                    if (ei[e] >= 0 && ej[e] > k)
                        D0[ei[e] * 36 + ej[e]] -= D0[ei[e] * 36 + k] * D0[ej[e] * 36 + k] * rinv;
                }
                __threadfence_block();
            }
            // finalize: diag = sqrt, off-diag /= d_j
#pragma unroll
            for (int e = 0; e < 9; ++e)
                if (ei[e] >= 0 && ei[e] == ej[e]) D0[ei[e] * 37] = sqrtf(D0[ei[e] * 37]);
            __threadfence_block();
#pragma unroll
            for (int e = 0; e < 9; ++e)
                if (ei[e] >= 0 && ei[e] > ej[e]) D0[ei[e] * 36 + ej[e]] /= D0[ej[e] * 37];
            // zero DinvSq
            for (int idx = tid; idx < 1024; idx += 64)
                DS[(idx >> 5) * 36 + (idx & 31)] = 0.f;
            __threadfence_block();
            // triangular inverse, lane cc owns column cc (lane-independent)
            if (tid < 32) {
                int cc = tid;
                float xv = 1.f / D0[cc * 37];
                DS[cc * 36 + cc] = xv;
                Lp[PAD(k0 + cc) + k0 + cc] = xv;
                for (int i = cc + 1; i < 32; ++i) {
                    float s = 0.f;
                    for (int k = cc; k < i; ++k)
                        s += D0[i * 36 + k] * DS[k * 36 + cc];
                    float v = -s / D0[i * 37];
                    DS[i * 36 + cc] = v;
                    Lp[PAD(k0 + i) + k0 + cc] = v;
                }
            }
        }
        __syncthreads();

        // panel solve: L21 = A21 * Dinv^T (branch-free via zero-padded DinvSq)
        {
            int m = 224 - k0;
            int r = tid >> 1, g = tid & 1;
            if (r < m) {
                int abase = PAD(k0 + 32 + r) + k0;
                float4 a[8];
#pragma unroll
                for (int q = 0; q < 8; ++q) a[q] = *(const float4*)&Lp[abase + q * 4];
#pragma unroll
                for (int tgrp = 0; tgrp < 4; ++tgrp) {
                    int cbase = g * 16 + tgrp * 4;
                    float rv[4];
#pragma unroll
                    for (int cc = 0; cc < 4; ++cc) {
                        const float* drow = &DS[(cbase + cc) * 36];
                        float s = 0.f;
#pragma unroll
                        for (int q = 0; q < 8; ++q) {
                            float4 d4 = *(const float4*)&drow[q * 4];
                            s += a[q].x*d4.x + a[q].y*d4.y + a[q].z*d4.z + a[q].w*d4.w;
                        }
                        rv[cc] = s;
                    }
                    float4 res; res.x = rv[0]; res.y = rv[1]; res.z = rv[2]; res.w = rv[3];
                    *(float4*)&Lp[abase + cbase] = res;
                }
            }
        }
        __syncthreads();

        // trailing update: A22 -= L21 L21^T (split pairs across row-stripes)
        {
            int npairs = TRI(7 - kb);
            if (npairs > 0) {
                int lsp = (npairs >= 8) ? 0 : (npairs >= 3 ? 1 : 2);
                int splitR = 1 << lsp;
                int units = npairs << lsp;
                int rows_pu = 32 >> lsp;
                for (int u = slot; u < units; u += 8) {
                    int p = u >> lsp, rpart = u & (splitR - 1);
                    int a2 = 0;
                    while (TRI(a2 + 1) <= p) ++a2;
                    int b2 = p - TRI(a2);
                    int ib2 = kb + 1 + a2, jb2 = kb + 1 + b2;
                    int nrq = rows_pu >> 3;
                    int r4 = rpart * rows_pu + (sub >> 3) * nrq;
                    if (lsp == 0)      trail_unit<4>(Lp, k0, ib2, jb2, r4, c4);
                    else if (lsp == 1) trail_unit<2>(Lp, k0, ib2, jb2, r4, c4);
                    else               trail_unit<1>(Lp, k0, ib2, jb2, r4, c4);
                }
            }
        }
        __syncthreads();
    }

    // ---------- blocked inverse (chunks of ≤4 jbb, split row-stripes) ----------
    for (int ib2 = 1; ib2 < 8; ++ib2) {
        for (int c0 = 0; c0 < ib2; c0 += 4) {
            int nc = (ib2 - c0 < 4) ? (ib2 - c0) : 4;
            int lsp = (nc <= 2) ? 2 : 1;
            int splitR = 1 << lsp;
            int units = nc << lsp;
            int rows_pu = 32 >> lsp;
            int nrq = rows_pu >> 3;
            for (int u = slot; u < units; u += 8) {
                int jj = u >> lsp, rpart = u & (splitR - 1);
                int jb2 = c0 + jj;
                int r4 = rpart * rows_pu + (sub >> 3) * nrq;
                float* Tst = &Dtmp[jj][0][0];
                if (lsp == 1) inv_t_unit<2>(Lp, Tst, ib2, jb2, r4, c4);
                else          inv_t_unit<1>(Lp, Tst, ib2, jb2, r4, c4);
            }
            __syncthreads();
            for (int u = slot; u < units; u += 8) {
                int jj = u >> lsp, rpart = u & (splitR - 1);
                int jb2 = c0 + jj;
                int r4 = rpart * rows_pu + (sub >> 3) * nrq;
                float* Tst = &Dtmp[jj][0][0];
                if (lsp == 1) inv_w_unit<2>(Lp, Tst, ib2, jb2, r4, c4);
                else          inv_w_unit<1>(Lp, Tst, ib2, jb2, r4, c4);
            }
            __syncthreads();
        }
    }

    // ---------- epilogue: bias and gamma-folded W ----------
    if (tid < 256) {
        int base = PAD(tid);
        float wm = 0.f;
        int nf = (tid + 1) & ~3;
        for (int q4 = 0; q4 < nf; q4 += 4) {
            float4 lv = *(const float4*)&Lp[base + q4];
            float4 mv = *(const float4*)&ms[q4];
            wm += lv.x*mv.x + lv.y*mv.y + lv.z*mv.z + lv.w*mv.w;
        }
        for (int j = nf; j <= tid; ++j) wm += Lp[base + j] * ms[j];
        bias[tid] = beta[tid] - gamma[tid] * wm;
    }
    for (int l = tid; l < 16384; l += 512) {
        int i = l >> 6, j0 = (l & 63) << 2;
        float4 w = *(const float4*)&Lp[PAD(i) + j0];
        float g = gamma[i];
        float4 o;
        o.x = (j0     <= i) ? w.x * g : 0.f;
        o.y = (j0 + 1 <= i) ? w.y * g : 0.f;
        o.z = (j0 + 2 <= i) ? w.z * g : 0.f;
        o.w = (j0 + 3 <= i) ? w.w * g : 0.f;
        *(float4*)&Wg[i * C + j0] = o;
    }
}

// ---------------- K4: out = x * Wg^T + bias ----------------
__global__ __launch_bounds__(256) void k_apply(const float* __restrict__ x,
                                               const float* __restrict__ Wg,
                                               const float* __restrict__ bias,
                                               float* __restrict__ out) {
    __shared__ __align__(16) float xsT[32][68];    // [k][row]
    __shared__ __align__(16) float wsT[32][260];   // [k][col]
    int tid = threadIdx.x;
    int wave = tid >> 6, lane = tid & 63;
    int r0 = blockIdx.x * 64;

    float4 acc4[16];
#pragma unroll
    for (int m = 0; m < 16; ++m) acc4[m] = make_float4(0.f, 0.f, 0.f, 0.f);

    for (int kc = 0; kc < C; kc += 32) {
        __syncthreads();
        for (int l = tid; l < 2048; l += 256) {
            int r = l >> 5, k = l & 31;
            xsT[k][r] = x[(size_t)(r0 + r) * C + kc + k];
        }
        for (int l = tid; l < 8192; l += 256) {
            int col = l >> 5, k = l & 31;
            wsT[k][col] = Wg[col * C + kc + k];
        }
        __syncthreads();
#pragma unroll 8
        for (int k = 0; k < 32; ++k) {
            float4 b4 = *(const float4*)&wsT[k][lane * 4];
#pragma unroll
            for (int mm = 0; mm < 4; ++mm) {
                float4 a4 = *(const float4*)&xsT[k][wave * 16 + mm * 4];
                float av[4] = {a4.x, a4.y, a4.z, a4.w};
#pragma unroll
                for (int t = 0; t < 4; ++t) {
                    acc4[mm * 4 + t].x += av[t] * b4.x;
                    acc4[mm * 4 + t].y += av[t] * b4.y;
                    acc4[mm * 4 + t].z += av[t] * b4.z;
                    acc4[mm * 4 + t].w += av[t] * b4.w;
                }
            }
        }
    }

    float4 bias4 = *(const float4*)&bias[lane * 4];
#pragma unroll
    for (int m = 0; m < 16; ++m) {
        int r = r0 + wave * 16 + m;
        float4 v;
        v.x = acc4[m].x + bias4.x;
        v.y = acc4[m].y + bias4.y;
        v.z = acc4[m].z + bias4.z;
        v.w = acc4[m].w + bias4.w;
        *(float4*)&out[(size_t)r * C + lane * 4] = v;
    }
}

extern "C" void kernel_launch(void* const* d_in, const int* in_sizes, int n_in,
                              void* d_out, int out_size, void* d_ws, size_t ws_size,
                              hipStream_t stream) {
    const float* x     = (const float*)d_in[0];
    const float* gamma = (const float*)d_in[1];
    const float* beta  = (const float*)d_in[2];
    float* out  = (float*)d_out;
    float* ws   = (float*)d_ws;
    float* sums = ws;                    // 256
    float* S    = ws + 256;              // 65536
    float* Wg   = ws + 256 + 65536;      // 65536
    float* bias = ws + 256 + 2 * 65536;  // 256

    hipMemsetAsync(ws, 0, (256 + 65536) * sizeof(float), stream);
    hipLaunchKernelGGL(k_cov, dim3(10, 64), dim3(256), 0, stream, x, S, sums);
    hipLaunchKernelGGL(k_chol, dim3(1), dim3(512), 0, stream, S, sums, gamma, beta, Wg, bias);
    hipLaunchKernelGGL(k_apply, dim3(3136), dim3(256), 0, stream, x, Wg, bias, out);
}

// Round 6
// 1092.081 us; speedup vs baseline: 4.2678x; 1.2331x over previous
//
#include <hip/hip_runtime.h>
#include <hip/hip_bf16.h>
#include <math.h>

#define C 256
#define NROWS (64*56*56)   // 200704
#define EPSV 0.001f
#define TRI(i) (((i)*((i)+1))>>1)

// padded packed-lower-triangle layout: row i starts at PAD(i), rows rounded to 4 floats
__device__ __forceinline__ int PAD(int i) {
    int a = i >> 2, b = i & 3;
    return ((a + 1) * (2 * a + b)) << 2;
}
// total size: PAD(255)+256 = 33280 floats

__device__ __forceinline__ float bcastf(float v, int l) {
    return __int_as_float(__builtin_amdgcn_readlane(__float_as_int(v), l));
}

// ws layout (floats):
//  [0,256)          : channel sums
//  [256,65792)      : S = sum x x^T
//  [65792,66048)    : biasacc = sum_j W_ij m_j
//  [66048,99328)    : Lg = factored triangle (padded layout; diag blocks = Dinv)
//  [99328,164864)   : Wg = gamma-folded L^{-1}

// ---------------- K2: raw second moment S + fused channel sums ----------------
__global__ __launch_bounds__(256) void k_cov(const float* __restrict__ x,
                                             float* __restrict__ S,
                                             float* __restrict__ sums) {
    __shared__ __align__(16) float as[64][68];
    __shared__ __align__(16) float bs[64][68];
    int t = blockIdx.x;        // 0..9  lower-triangular tile pair
    int slice = blockIdx.y;    // 0..63
    int ti = 0;
    while (((ti + 1) * (ti + 2)) / 2 <= t) ++ti;
    int tj = t - (ti * (ti + 1)) / 2;
    int ci = ti * 64, cj = tj * 64;
    bool isdiag = (ti == tj);
    const int rows_per_slice = NROWS / 64;   // 3136
    int r0 = slice * rows_per_slice;
    int tid = threadIdx.x;
    int ia = (tid >> 4) * 4;
    int jb = (tid & 15) * 4;

    float acc[4][4];
#pragma unroll
    for (int a = 0; a < 4; ++a)
#pragma unroll
        for (int b = 0; b < 4; ++b) acc[a][b] = 0.f;
    float colsum = 0.f;

    for (int ch = 0; ch < rows_per_slice; ch += 64) {
        __syncthreads();
        for (int l = tid; l < 4096; l += 256) {
            int r = l >> 6, c = l & 63;
            const float* row = x + (size_t)(r0 + ch + r) * C;
            float av = row[ci + c];
            as[r][c] = av;
            bs[r][c] = row[cj + c];
            if (isdiag) colsum += av;
        }
        __syncthreads();
#pragma unroll 4
        for (int r = 0; r < 64; ++r) {
            float4 a4 = *(const float4*)&as[r][ia];
            float4 b4 = *(const float4*)&bs[r][jb];
            float av[4] = {a4.x, a4.y, a4.z, a4.w};
            float bv[4] = {b4.x, b4.y, b4.z, b4.w};
#pragma unroll
            for (int ii = 0; ii < 4; ++ii)
#pragma unroll
                for (int jj = 0; jj < 4; ++jj)
                    acc[ii][jj] += av[ii] * bv[jj];
        }
    }
#pragma unroll
    for (int ii = 0; ii < 4; ++ii)
#pragma unroll
        for (int jj = 0; jj < 4; ++jj)
            atomicAdd(&S[(ci + ia + ii) * C + (cj + jb + jj)], acc[ii][jj]);
    if (isdiag) atomicAdd(&sums[ci + (tid & 63)], colsum);
}

// ---------------- trailing-update helper (templated NR keeps indexing static) ----------------
template<int NR>
__device__ __forceinline__ void trail_unit(float* __restrict__ Lp, int k0,
                                           int ib2, int jb2, int r4, int c4) {
    int gj = jb2 * 32 + c4;
    int brow[4], arow[NR];
#pragma unroll
    for (int cc = 0; cc < 4; ++cc) brow[cc] = PAD(gj + cc) + k0;
#pragma unroll
    for (int rr = 0; rr < NR; ++rr) arow[rr] = PAD(ib2 * 32 + r4 + rr) + k0;
    float acc[NR][4];
#pragma unroll
    for (int rr = 0; rr < NR; ++rr)
#pragma unroll
        for (int cc = 0; cc < 4; ++cc) acc[rr][cc] = 0.f;
#pragma unroll
    for (int k4 = 0; k4 < 32; k4 += 4) {
        float4 b0 = *(const float4*)&Lp[brow[0] + k4];
        float4 b1 = *(const float4*)&Lp[brow[1] + k4];
        float4 b2 = *(const float4*)&Lp[brow[2] + k4];
        float4 b3 = *(const float4*)&Lp[brow[3] + k4];
#pragma unroll
        for (int rr = 0; rr < NR; ++rr) {
            float4 av = *(const float4*)&Lp[arow[rr] + k4];
            acc[rr][0] += av.x*b0.x + av.y*b0.y + av.z*b0.z + av.w*b0.w;
            acc[rr][1] += av.x*b1.x + av.y*b1.y + av.z*b1.z + av.w*b1.w;
            acc[rr][2] += av.x*b2.x + av.y*b2.y + av.z*b2.z + av.w*b2.w;
            acc[rr][3] += av.x*b3.x + av.y*b3.y + av.z*b3.z + av.w*b3.w;
        }
    }
    if (ib2 != jb2) {
#pragma unroll
        for (int rr = 0; rr < NR; ++rr) {
            int wb = PAD(ib2 * 32 + r4 + rr) + gj;
            float4 o = *(const float4*)&Lp[wb];
            o.x -= acc[rr][0]; o.y -= acc[rr][1]; o.z -= acc[rr][2]; o.w -= acc[rr][3];
            *(float4*)&Lp[wb] = o;
        }
    } else {
#pragma unroll
        for (int rr = 0; rr < NR; ++rr) {
            int rloc = r4 + rr;
            int wb = PAD(ib2 * 32 + rloc) + gj;
#pragma unroll
            for (int cc = 0; cc < 4; ++cc)
                if (c4 + cc <= rloc) Lp[wb + cc] -= acc[rr][cc];
        }
    }
}

// ---------------- K3a: factorization (1 block). Register-resident diag factor+inverse ----------------
__global__ __launch_bounds__(512, 2) void k_fact(const float* __restrict__ S,
                                                 const float* __restrict__ sums,
                                                 float* __restrict__ Lg) {
    __shared__ __align__(16) float Lp[33280];   // 133.1 KB padded triangle
    __shared__ float ms[256];
    __shared__ __align__(16) float DS[32 * 36]; // Dinv square, row-major, zero-filled upper
    int tid = threadIdx.x;
    if (tid < 256) ms[tid] = sums[tid] * (1.f / (float)NROWS);
    __syncthreads();

    const float scale = (1.f - EPSV) / ((float)NROWS - 1.f);
    // FIX (round 5): full triangle init — 256 rows x 64 float4 column-groups.
    for (int u = tid; u < 16384; u += 512) {
        int i = u >> 6, j0 = (u & 63) << 2;
        if (j0 <= i) {
            float4 s4 = *(const float4*)&S[i * C + j0];
            float vs[4] = {s4.x, s4.y, s4.z, s4.w};
            float miN = ms[i] * (float)NROWS;
            int base = PAD(i);
#pragma unroll
            for (int e = 0; e < 4; ++e) {
                int j = j0 + e;
                if (j <= i) {
                    float v = (vs[e] - miN * ms[j]) * scale;
                    if (j == i) v += EPSV;
                    Lp[base + j] = v;
                }
            }
        }
    }
    __syncthreads();

    int lane = tid & 63;
    int slot = tid >> 6, sub = tid & 63;
    int c4 = (sub & 7) * 4;

    for (int kb = 0; kb < 8; ++kb) {
        int k0 = kb * 32;

        // ---- diag factor + triangular inverse, fully in wave-0 registers ----
        if (tid < 64) {
            int col = lane & 31;
            float a[32];
#pragma unroll
            for (int i = 0; i < 32; ++i) {
                int ii = (i >= col) ? i : col;
                int jj = (i >= col) ? col : i;
                a[i] = Lp[PAD(k0 + ii) + k0 + jj];
            }
            float drec = 0.f;
#pragma unroll
            for (int k = 0; k < 32; ++k) {
                float akk = bcastf(a[k], k);
                float rinv = rsqrtf(akk);
                float myl = a[k] * rinv;        // current a_{col,k} scaled
                bool up = (col > k);
#pragma unroll
                for (int i = k + 1; i < 32; ++i) {
                    float lik = bcastf(a[i], k) * rinv;
                    if (up) a[i] -= lik * myl;
                    if (col == k) a[i] = lik;
                }
                if (col == k) { a[k] = akk * rinv; drec = rinv; }
            }
            // forward substitution: xv = column `col` of Dinv
            float xv[32];
#pragma unroll
            for (int i = 0; i < 32; ++i) xv[i] = (col == i) ? 1.f : 0.f;
#pragma unroll
            for (int i = 0; i < 32; ++i) {
                float di = bcastf(drec, i);
                float xi = xv[i] * di;
                xv[i] = xi;
#pragma unroll
                for (int j = i + 1; j < 32; ++j) {
                    float lji = bcastf(a[j], i);
                    xv[j] -= lji * xi;
                }
            }
            if (lane < 32) {
#pragma unroll
                for (int i = 0; i < 32; ++i) {
                    DS[i * 36 + col] = xv[i];                       // full square, zeros above
                    if (i >= col) Lp[PAD(k0 + i) + k0 + col] = xv[i]; // diag block := Dinv
                }
            }
        }
        __syncthreads();

        // ---- panel solve: L21 = A21 * Dinv^T (branch-free via zero-padded DS) ----
        {
            int m = 224 - k0;
            int r = tid >> 1, g = tid & 1;
            if (r < m) {
                int abase = PAD(k0 + 32 + r) + k0;
                float4 av[8];
#pragma unroll
                for (int q = 0; q < 8; ++q) av[q] = *(const float4*)&Lp[abase + q * 4];
#pragma unroll
                for (int tgrp = 0; tgrp < 4; ++tgrp) {
                    int cbase = g * 16 + tgrp * 4;
                    float rv[4];
#pragma unroll
                    for (int cc = 0; cc < 4; ++cc) {
                        const float* drow = &DS[(cbase + cc) * 36];
                        float s = 0.f;
#pragma unroll
                        for (int q = 0; q < 8; ++q) {
                            float4 d4 = *(const float4*)&drow[q * 4];
                            s += av[q].x*d4.x + av[q].y*d4.y + av[q].z*d4.z + av[q].w*d4.w;
                        }
                        rv[cc] = s;
                    }
                    float4 res; res.x = rv[0]; res.y = rv[1]; res.z = rv[2]; res.w = rv[3];
                    *(float4*)&Lp[abase + cbase] = res;
                }
            }
        }
        __syncthreads();

        // ---- trailing update: A22 -= L21 L21^T ----
        {
            int npairs = TRI(7 - kb);
            if (npairs > 0) {
                int lsp = (npairs >= 8) ? 0 : (npairs >= 3 ? 1 : 2);
                int splitR = 1 << lsp;
                int units = npairs << lsp;
                int rows_pu = 32 >> lsp;
                for (int u = slot; u < units; u += 8) {
                    int p = u >> lsp, rpart = u & (splitR - 1);
                    int a2 = 0;
                    while (TRI(a2 + 1) <= p) ++a2;
                    int b2 = p - TRI(a2);
                    int ib2 = kb + 1 + a2, jb2 = kb + 1 + b2;
                    int nrq = rows_pu >> 3;
                    int r4 = rpart * rows_pu + (sub >> 3) * nrq;
                    if (lsp == 0)      trail_unit<4>(Lp, k0, ib2, jb2, r4, c4);
                    else if (lsp == 1) trail_unit<2>(Lp, k0, ib2, jb2, r4, c4);
                    else               trail_unit<1>(Lp, k0, ib2, jb2, r4, c4);
                }
            }
        }
        __syncthreads();
    }

    // write triangle to global (L2-resident) for k_inv
    for (int u = tid; u < 8320; u += 512)
        *(float4*)&Lg[u * 4] = *(const float4*)&Lp[u * 4];
}

// ---------------- K3b: blocked inverse, one block per W column-block (+ epilogue) ----------------
__global__ __launch_bounds__(256) void k_inv(const float* __restrict__ Lg,
                                             const float* __restrict__ sums,
                                             const float* __restrict__ gamma,
                                             float* __restrict__ Wg,
                                             float* __restrict__ biasacc) {
    __shared__ __align__(16) float Wcol[256][36];  // 36.9 KB
    __shared__ __align__(16) float Ls[32][36];
    __shared__ __align__(16) float Tst[32][36];
    int jbb = blockIdx.x;      // 0..7
    int tid = threadIdx.x;
    int j0 = jbb * 32;

    // load Dinv_jbb (zero upper) into Wcol rows [j0, j0+32)
    {
        int r = tid >> 3, cq = (tid & 7) * 4;
        const float* row = &Lg[PAD(j0 + r) + j0];
        float4 v;
        v.x = (cq     <= r) ? row[cq]     : 0.f;
        v.y = (cq + 1 <= r) ? row[cq + 1] : 0.f;
        v.z = (cq + 2 <= r) ? row[cq + 2] : 0.f;
        v.w = (cq + 3 <= r) ? row[cq + 3] : 0.f;
        *(float4*)&Wcol[j0 + r][cq] = v;
    }
    __syncthreads();

    int r2 = (tid >> 4) * 2, c2 = (tid & 15) * 2;
    for (int ib = jbb + 1; ib < 8; ++ib) {
        int i0 = ib * 32;
        float t00 = 0, t01 = 0, t10 = 0, t11 = 0;
        for (int kb = jbb; kb < ib; ++kb) {
            __syncthreads();   // protects Ls reuse + prior Wcol writes
            {
                int r = tid >> 3, cq = (tid & 7) * 4;
                *(float4*)&Ls[r][cq] = *(const float4*)&Lg[PAD(i0 + r) + kb * 32 + cq];
            }
            __syncthreads();
            int kw = kb * 32;
#pragma unroll 8
            for (int q = 0; q < 32; ++q) {
                float l0 = Ls[r2][q], l1 = Ls[r2 + 1][q];
                float w0 = Wcol[kw + q][c2], w1 = Wcol[kw + q][c2 + 1];
                t00 += l0 * w0; t01 += l0 * w1;
                t10 += l1 * w0; t11 += l1 * w1;
            }
        }
        __syncthreads();
        Tst[r2][c2] = t00;     Tst[r2][c2 + 1] = t01;
        Tst[r2 + 1][c2] = t10; Tst[r2 + 1][c2 + 1] = t11;
        {
            int r = tid >> 3, cq = (tid & 7) * 4;
            const float* row = &Lg[PAD(i0 + r) + i0];
            float4 v;
            v.x = (cq     <= r) ? row[cq]     : 0.f;
            v.y = (cq + 1 <= r) ? row[cq + 1] : 0.f;
            v.z = (cq + 2 <= r) ? row[cq + 2] : 0.f;
            v.w = (cq + 3 <= r) ? row[cq + 3] : 0.f;
            *(float4*)&Ls[r][cq] = v;   // Dinv_ib, zero upper
        }
        __syncthreads();
        float w00 = 0, w01 = 0, w10 = 0, w11 = 0;
#pragma unroll 8
        for (int q = 0; q < 32; ++q) {
            float d0 = Ls[r2][q], d1 = Ls[r2 + 1][q];
            float tq0 = Tst[q][c2], tq1 = Tst[q][c2 + 1];
            w00 += d0 * tq0; w01 += d0 * tq1;
            w10 += d1 * tq0; w11 += d1 * tq1;
        }
        Wcol[i0 + r2][c2] = -w00;     Wcol[i0 + r2][c2 + 1] = -w01;
        Wcol[i0 + r2 + 1][c2] = -w10; Wcol[i0 + r2 + 1][c2 + 1] = -w11;
    }
    __syncthreads();

    // bias partial: biasacc[r] += sum_c W[r][j0+c] * m[j0+c]
    {
        int r = tid;
        if (r >= j0) {
            float s = 0.f;
#pragma unroll 8
            for (int c = 0; c < 32; ++c)
                s += Wcol[r][c] * sums[j0 + c];
            atomicAdd(&biasacc[r], s * (1.f / (float)NROWS));
        }
    }
    // Wg columns [j0, j0+32), all 256 rows (zeros above diag blocks)
    for (int u = tid; u < 2048; u += 256) {
        int r = u >> 3, cq = (u & 7) * 4;
        float4 o;
        if (r < j0) {
            o = make_float4(0.f, 0.f, 0.f, 0.f);
        } else {
            float g = gamma[r];
            o = *(const float4*)&Wcol[r][cq];
            o.x *= g; o.y *= g; o.z *= g; o.w *= g;
        }
        *(float4*)&Wg[r * C + j0 + cq] = o;
    }
}

// ---------------- K4: out = x * Wg^T + (beta - gamma*biasacc) ----------------
__global__ __launch_bounds__(256) void k_apply(const float* __restrict__ x,
                                               const float* __restrict__ Wg,
                                               const float* __restrict__ beta,
                                               const float* __restrict__ gamma,
                                               const float* __restrict__ biasacc,
                                               float* __restrict__ out) {
    __shared__ __align__(16) float xsT[32][68];    // [k][row]
    __shared__ __align__(16) float wsT[32][260];   // [k][col]
    int tid = threadIdx.x;
    int wave = tid >> 6, lane = tid & 63;
    int r0 = blockIdx.x * 64;

    float4 acc4[16];
#pragma unroll
    for (int m = 0; m < 16; ++m) acc4[m] = make_float4(0.f, 0.f, 0.f, 0.f);

    for (int kc = 0; kc < C; kc += 32) {
        __syncthreads();
        for (int l = tid; l < 2048; l += 256) {
            int r = l >> 5, k = l & 31;
            xsT[k][r] = x[(size_t)(r0 + r) * C + kc + k];
        }
        for (int l = tid; l < 8192; l += 256) {
            int col = l >> 5, k = l & 31;
            wsT[k][col] = Wg[col * C + kc + k];
        }
        __syncthreads();
#pragma unroll 8
        for (int k = 0; k < 32; ++k) {
            float4 b4 = *(const float4*)&wsT[k][lane * 4];
#pragma unroll
            for (int mm = 0; mm < 4; ++mm) {
                float4 a4 = *(const float4*)&xsT[k][wave * 16 + mm * 4];
                float av[4] = {a4.x, a4.y, a4.z, a4.w};
#pragma unroll
                for (int t = 0; t < 4; ++t) {
                    acc4[mm * 4 + t].x += av[t] * b4.x;
                    acc4[mm * 4 + t].y += av[t] * b4.y;
                    acc4[mm * 4 + t].z += av[t] * b4.z;
                    acc4[mm * 4 + t].w += av[t] * b4.w;
                }
            }
        }
    }

    float4 be = *(const float4*)&beta[lane * 4];
    float4 ga = *(const float4*)&gamma[lane * 4];
    float4 ba = *(const float4*)&biasacc[lane * 4];
    float4 bias4;
    bias4.x = be.x - ga.x * ba.x;
    bias4.y = be.y - ga.y * ba.y;
    bias4.z = be.z - ga.z * ba.z;
    bias4.w = be.w - ga.w * ba.w;
#pragma unroll
    for (int m = 0; m < 16; ++m) {
        int r = r0 + wave * 16 + m;
        float4 v;
        v.x = acc4[m].x + bias4.x;
        v.y = acc4[m].y + bias4.y;
        v.z = acc4[m].z + bias4.z;
        v.w = acc4[m].w + bias4.w;
        *(float4*)&out[(size_t)r * C + lane * 4] = v;
    }
}

extern "C" void kernel_launch(void* const* d_in, const int* in_sizes, int n_in,
                              void* d_out, int out_size, void* d_ws, size_t ws_size,
                              hipStream_t stream) {
    const float* x     = (const float*)d_in[0];
    const float* gamma = (const float*)d_in[1];
    const float* beta  = (const float*)d_in[2];
    float* out  = (float*)d_out;
    float* ws   = (float*)d_ws;
    float* sums     = ws;            // 256
    float* S        = ws + 256;      // 65536
    float* biasacc  = ws + 65792;    // 256
    float* Lg       = ws + 66048;    // 33280
    float* Wg       = ws + 99328;    // 65536

    hipMemsetAsync(ws, 0, 66048 * sizeof(float), stream);
    hipLaunchKernelGGL(k_cov, dim3(10, 64), dim3(256), 0, stream, x, S, sums);
    hipLaunchKernelGGL(k_fact, dim3(1), dim3(512), 0, stream, S, sums, Lg);
    hipLaunchKernelGGL(k_inv, dim3(8), dim3(256), 0, stream, Lg, sums, gamma, Wg, biasacc);
    hipLaunchKernelGGL(k_apply, dim3(3136), dim3(256), 0, stream, x, Wg, beta, gamma, biasacc, out);
}

// Round 7
// 902.719 us; speedup vs baseline: 5.1631x; 1.2098x over previous
//
#include <hip/hip_runtime.h>
#include <hip/hip_bf16.h>
#include <math.h>

#define C 256
#define NROWS (64*56*56)   // 200704
#define EPSV 0.001f
#define TRI(i) (((i)*((i)+1))>>1)

typedef __attribute__((ext_vector_type(8))) short bf16x8;
typedef __attribute__((ext_vector_type(4))) float f32x4;
#define MFMA16 __builtin_amdgcn_mfma_f32_16x16x32_bf16

// padded packed-lower-triangle layout: row i starts at PAD(i), rows rounded to 4 floats
__device__ __forceinline__ int PAD(int i) {
    int a = i >> 2, b = i & 3;
    return ((a + 1) * (2 * a + b)) << 2;
}
// total size: PAD(255)+256 = 33280 floats

__device__ __forceinline__ float bcastf(float v, int l) {
    return __int_as_float(__builtin_amdgcn_readlane(__float_as_int(v), l));
}

// split two f32 into packed bf16 hi (truncated) and bf16 lo (residual)
__device__ __forceinline__ void split2(float v0, float v1, unsigned& hi, unsigned& lo) {
    unsigned b0 = __float_as_uint(v0), b1 = __float_as_uint(v1);
    hi = (b0 >> 16) | (b1 & 0xFFFF0000u);
    float l0 = v0 - __uint_as_float(b0 & 0xFFFF0000u);
    float l1 = v1 - __uint_as_float(b1 & 0xFFFF0000u);
    lo = (__float_as_uint(l0) >> 16) | (__float_as_uint(l1) & 0xFFFF0000u);
}

// split 8 contiguous f32 into bf16x8 hi/lo fragments
__device__ __forceinline__ void split8(const float* p, bf16x8& h, bf16x8& l) {
    f32x4 v0 = *(const f32x4*)p;
    f32x4 v1 = *(const f32x4*)(p + 4);
#pragma unroll
    for (int e = 0; e < 4; ++e) {
        unsigned b = __float_as_uint(v0[e]);
        h[e] = (short)(b >> 16);
        float lf = v0[e] - __uint_as_float(b & 0xFFFF0000u);
        l[e] = (short)(__float_as_uint(lf) >> 16);
        unsigned b2 = __float_as_uint(v1[e]);
        h[4 + e] = (short)(b2 >> 16);
        float lf2 = v1[e] - __uint_as_float(b2 & 0xFFFF0000u);
        l[4 + e] = (short)(__float_as_uint(lf2) >> 16);
    }
}

// ws layout (floats):
//  [0,256)          : channel sums
//  [256,512)        : biasacc
//  [512,524800)     : S8 = 8 copies of S partials (8*65536)
//  [524800,558080)  : Lg  = factored triangle
//  [558080,590848)  : Wghi (65536 bf16 as ushort)
//  [590848,623616)  : Wglo

// ---------------- K2: S = X^T X via bf16-split MFMA + fused channel sums ----------------
// Wave W owns lower-tri 16x16 tile rows {W, 7-W, 8+W, 15-W} (34 tiles, static indexing).
template<int W>
__device__ __forceinline__ void cov_step(f32x4* acc, const unsigned* lh, const unsigned* ll,
                                         int m, int kg) {
    constexpr int R0 = W, R1 = 7 - W, R2 = 8 + W, R3 = 15 - W;
    constexpr int O0 = 0, O1 = W + 1, O2 = 9, O3 = 18 + W;
    bf16x8 ah[4], al[4];
    {
        int o0 = (R0 * 16 + m) * 20 + kg * 4;
        int o1 = (R1 * 16 + m) * 20 + kg * 4;
        int o2 = (R2 * 16 + m) * 20 + kg * 4;
        int o3 = (R3 * 16 + m) * 20 + kg * 4;
        ah[0] = *(const bf16x8*)&lh[o0]; al[0] = *(const bf16x8*)&ll[o0];
        ah[1] = *(const bf16x8*)&lh[o1]; al[1] = *(const bf16x8*)&ll[o1];
        ah[2] = *(const bf16x8*)&lh[o2]; al[2] = *(const bf16x8*)&ll[o2];
        ah[3] = *(const bf16x8*)&lh[o3]; al[3] = *(const bf16x8*)&ll[o3];
    }
#pragma unroll
    for (int c = 0; c <= R3; ++c) {
        int o = (c * 16 + m) * 20 + kg * 4;
        bf16x8 bh = *(const bf16x8*)&lh[o];
        bf16x8 bl = *(const bf16x8*)&ll[o];
        if (c <= R0) {
            acc[O0 + c] = MFMA16(ah[0], bh, acc[O0 + c], 0, 0, 0);
            acc[O0 + c] = MFMA16(ah[0], bl, acc[O0 + c], 0, 0, 0);
            acc[O0 + c] = MFMA16(al[0], bh, acc[O0 + c], 0, 0, 0);
        }
        if (c <= R1) {
            acc[O1 + c] = MFMA16(ah[1], bh, acc[O1 + c], 0, 0, 0);
            acc[O1 + c] = MFMA16(ah[1], bl, acc[O1 + c], 0, 0, 0);
            acc[O1 + c] = MFMA16(al[1], bh, acc[O1 + c], 0, 0, 0);
        }
        if (c <= R2) {
            acc[O2 + c] = MFMA16(ah[2], bh, acc[O2 + c], 0, 0, 0);
            acc[O2 + c] = MFMA16(ah[2], bl, acc[O2 + c], 0, 0, 0);
            acc[O2 + c] = MFMA16(al[2], bh, acc[O2 + c], 0, 0, 0);
        }
        {
            acc[O3 + c] = MFMA16(ah[3], bh, acc[O3 + c], 0, 0, 0);
            acc[O3 + c] = MFMA16(ah[3], bl, acc[O3 + c], 0, 0, 0);
            acc[O3 + c] = MFMA16(al[3], bh, acc[O3 + c], 0, 0, 0);
        }
    }
}

template<int W>
__device__ __forceinline__ void cov_out(const f32x4* acc, float* Sc, int m, int kg) {
    constexpr int R[4] = {W, 7 - W, 8 + W, 15 - W};
    constexpr int O[4] = {0, W + 1, 9, 18 + W};
#pragma unroll
    for (int rr = 0; rr < 4; ++rr) {
        int i0 = R[rr] * 16 + kg * 4;
#pragma unroll
        for (int c = 0; c < 16; ++c) {
            if (c <= R[rr]) {
                int j = c * 16 + m;
#pragma unroll
                for (int q = 0; q < 4; ++q)
                    atomicAdd(&Sc[(i0 + q) * 256 + j], acc[O[rr] + c][q]);
            }
        }
    }
}

__global__ __launch_bounds__(256, 1) void k_cov(const float* __restrict__ x,
                                                float* __restrict__ S8,
                                                float* __restrict__ sums) {
    __shared__ unsigned lh[256 * 20];   // xT hi: [ch][16 u32], stride 20 u32 (80B, 16B-aligned)
    __shared__ unsigned ll_[256 * 20];
    int tid = threadIdx.x, wave = tid >> 6, lane = tid & 63;
    int m = lane & 15, kg = lane >> 4;
    const float* xc = x + (size_t)blockIdx.x * 896 * 256 + tid;   // thread = channel
    f32x4 acc[34];
#pragma unroll
    for (int t = 0; t < 34; ++t) acc[t] = 0.f;
    float colsum = 0.f;

    for (int ch = 0; ch < 28; ++ch) {
        __syncthreads();
        const float* xr = xc + ch * 32 * 256;
#pragma unroll
        for (int rp = 0; rp < 16; ++rp) {
            float v0 = xr[(2 * rp) * 256];
            float v1 = xr[(2 * rp + 1) * 256];
            colsum += v0 + v1;
            unsigned h, l;
            split2(v0, v1, h, l);
            lh[tid * 20 + rp] = h;
            ll_[tid * 20 + rp] = l;
        }
        __syncthreads();
        if      (wave == 0) cov_step<0>(acc, lh, ll_, m, kg);
        else if (wave == 1) cov_step<1>(acc, lh, ll_, m, kg);
        else if (wave == 2) cov_step<2>(acc, lh, ll_, m, kg);
        else                cov_step<3>(acc, lh, ll_, m, kg);
    }
    atomicAdd(&sums[tid], colsum);
    float* Sc = S8 + (size_t)(blockIdx.x & 7) * 65536;
    if      (wave == 0) cov_out<0>(acc, Sc, m, kg);
    else if (wave == 1) cov_out<1>(acc, Sc, m, kg);
    else if (wave == 2) cov_out<2>(acc, Sc, m, kg);
    else                cov_out<3>(acc, Sc, m, kg);
}

// ---------------- trailing-update helper (templated NR keeps indexing static) ----------------
template<int NR>
__device__ __forceinline__ void trail_unit(float* __restrict__ Lp, int k0,
                                           int ib2, int jb2, int r4, int c4) {
    int gj = jb2 * 32 + c4;
    int brow[4], arow[NR];
#pragma unroll
    for (int cc = 0; cc < 4; ++cc) brow[cc] = PAD(gj + cc) + k0;
#pragma unroll
    for (int rr = 0; rr < NR; ++rr) arow[rr] = PAD(ib2 * 32 + r4 + rr) + k0;
    float acc[NR][4];
#pragma unroll
    for (int rr = 0; rr < NR; ++rr)
#pragma unroll
        for (int cc = 0; cc < 4; ++cc) acc[rr][cc] = 0.f;
#pragma unroll
    for (int k4 = 0; k4 < 32; k4 += 4) {
        float4 b0 = *(const float4*)&Lp[brow[0] + k4];
        float4 b1 = *(const float4*)&Lp[brow[1] + k4];
        float4 b2 = *(const float4*)&Lp[brow[2] + k4];
        float4 b3 = *(const float4*)&Lp[brow[3] + k4];
#pragma unroll
        for (int rr = 0; rr < NR; ++rr) {
            float4 av = *(const float4*)&Lp[arow[rr] + k4];
            acc[rr][0] += av.x*b0.x + av.y*b0.y + av.z*b0.z + av.w*b0.w;
            acc[rr][1] += av.x*b1.x + av.y*b1.y + av.z*b1.z + av.w*b1.w;
            acc[rr][2] += av.x*b2.x + av.y*b2.y + av.z*b2.z + av.w*b2.w;
            acc[rr][3] += av.x*b3.x + av.y*b3.y + av.z*b3.z + av.w*b3.w;
        }
    }
    if (ib2 != jb2) {
#pragma unroll
        for (int rr = 0; rr < NR; ++rr) {
            int wb = PAD(ib2 * 32 + r4 + rr) + gj;
            float4 o = *(const float4*)&Lp[wb];
            o.x -= acc[rr][0]; o.y -= acc[rr][1]; o.z -= acc[rr][2]; o.w -= acc[rr][3];
            *(float4*)&Lp[wb] = o;
        }
    } else {
#pragma unroll
        for (int rr = 0; rr < NR; ++rr) {
            int rloc = r4 + rr;
            int wb = PAD(ib2 * 32 + rloc) + gj;
#pragma unroll
            for (int cc = 0; cc < 4; ++cc)
                if (c4 + cc <= rloc) Lp[wb + cc] -= acc[rr][cc];
        }
    }
}

// ---------------- K3a: factorization (1 block). Register-resident diag factor+inverse ----------------
__global__ __launch_bounds__(512, 2) void k_fact(const float* __restrict__ S8,
                                                 const float* __restrict__ sums,
                                                 float* __restrict__ Lg) {
    __shared__ __align__(16) float Lp[33280];   // 133.1 KB padded triangle
    __shared__ float ms[256];
    __shared__ __align__(16) float DS[32 * 36]; // Dinv square, row-major, zero-filled upper
    int tid = threadIdx.x;
    if (tid < 256) ms[tid] = sums[tid] * (1.f / (float)NROWS);
    __syncthreads();

    const float scale = (1.f - EPSV) / ((float)NROWS - 1.f);
    for (int u = tid; u < 16384; u += 512) {
        int i = u >> 6, j0 = (u & 63) << 2;
        if (j0 <= i) {
            f32x4 s4 = 0.f;
#pragma unroll
            for (int p = 0; p < 8; ++p)
                s4 += *(const f32x4*)&S8[p * 65536 + i * C + j0];
            float miN = ms[i] * (float)NROWS;
            int base = PAD(i);
#pragma unroll
            for (int e = 0; e < 4; ++e) {
                int j = j0 + e;
                if (j <= i) {
                    float v = (s4[e] - miN * ms[j]) * scale;
                    if (j == i) v += EPSV;
                    Lp[base + j] = v;
                }
            }
        }
    }
    __syncthreads();

    int lane = tid & 63;
    int slot = tid >> 6, sub = tid & 63;
    int c4 = (sub & 7) * 4;

    for (int kb = 0; kb < 8; ++kb) {
        int k0 = kb * 32;

        // ---- diag factor + triangular inverse, fully in wave-0 registers ----
        if (tid < 64) {
            int col = lane & 31;
            float a[32];
#pragma unroll
            for (int i = 0; i < 32; ++i) {
                int ii = (i >= col) ? i : col;
                int jj = (i >= col) ? col : i;
                a[i] = Lp[PAD(k0 + ii) + k0 + jj];
            }
            float drec = 0.f;
#pragma unroll
            for (int k = 0; k < 32; ++k) {
                float akk = bcastf(a[k], k);
                float rinv = rsqrtf(akk);
                float myl = a[k] * rinv;
                bool up = (col > k);
#pragma unroll
                for (int i = k + 1; i < 32; ++i) {
                    float lik = bcastf(a[i], k) * rinv;
                    if (up) a[i] -= lik * myl;
                    if (col == k) a[i] = lik;
                }
                if (col == k) { a[k] = akk * rinv; drec = rinv; }
            }
            float xv[32];
#pragma unroll
            for (int i = 0; i < 32; ++i) xv[i] = (col == i) ? 1.f : 0.f;
#pragma unroll
            for (int i = 0; i < 32; ++i) {
                float di = bcastf(drec, i);
                float xi = xv[i] * di;
                xv[i] = xi;
#pragma unroll
                for (int j = i + 1; j < 32; ++j) {
                    float lji = bcastf(a[j], i);
                    xv[j] -= lji * xi;
                }
            }
            if (lane < 32) {
#pragma unroll
                for (int i = 0; i < 32; ++i) {
                    DS[i * 36 + col] = xv[i];
                    if (i >= col) Lp[PAD(k0 + i) + k0 + col] = xv[i];
                }
            }
        }
        __syncthreads();

        // ---- panel solve: L21 = A21 * Dinv^T ----
        {
            int m = 224 - k0;
            int r = tid >> 1, g = tid & 1;
            if (r < m) {
                int abase = PAD(k0 + 32 + r) + k0;
                float4 av[8];
#pragma unroll
                for (int q = 0; q < 8; ++q) av[q] = *(const float4*)&Lp[abase + q * 4];
#pragma unroll
                for (int tgrp = 0; tgrp < 4; ++tgrp) {
                    int cbase = g * 16 + tgrp * 4;
                    float rv[4];
#pragma unroll
                    for (int cc = 0; cc < 4; ++cc) {
                        const float* drow = &DS[(cbase + cc) * 36];
                        float s = 0.f;
#pragma unroll
                        for (int q = 0; q < 8; ++q) {
                            float4 d4 = *(const float4*)&drow[q * 4];
                            s += av[q].x*d4.x + av[q].y*d4.y + av[q].z*d4.z + av[q].w*d4.w;
                        }
                        rv[cc] = s;
                    }
                    float4 res; res.x = rv[0]; res.y = rv[1]; res.z = rv[2]; res.w = rv[3];
                    *(float4*)&Lp[abase + cbase] = res;
                }
            }
        }
        __syncthreads();

        // ---- trailing update ----
        {
            int npairs = TRI(7 - kb);
            if (npairs > 0) {
                int lsp = (npairs >= 8) ? 0 : (npairs >= 3 ? 1 : 2);
                int splitR = 1 << lsp;
                int units = npairs << lsp;
                int rows_pu = 32 >> lsp;
                for (int u = slot; u < units; u += 8) {
                    int p = u >> lsp, rpart = u & (splitR - 1);
                    int a2 = 0;
                    while (TRI(a2 + 1) <= p) ++a2;
                    int b2 = p - TRI(a2);
                    int ib2 = kb + 1 + a2, jb2 = kb + 1 + b2;
                    int nrq = rows_pu >> 3;
                    int r4 = rpart * rows_pu + (sub >> 3) * nrq;
                    if (lsp == 0)      trail_unit<4>(Lp, k0, ib2, jb2, r4, c4);
                    else if (lsp == 1) trail_unit<2>(Lp, k0, ib2, jb2, r4, c4);
                    else               trail_unit<1>(Lp, k0, ib2, jb2, r4, c4);
                }
            }
        }
        __syncthreads();
    }

    for (int u = tid; u < 8320; u += 512)
        *(float4*)&Lg[u * 4] = *(const float4*)&Lp[u * 4];
}

// ---------------- K3b: blocked inverse, one block per W column-block (+ bf16 split epilogue) ----------------
__global__ __launch_bounds__(256) void k_inv(const float* __restrict__ Lg,
                                             const float* __restrict__ sums,
                                             const float* __restrict__ gamma,
                                             unsigned short* __restrict__ Wghi,
                                             unsigned short* __restrict__ Wglo,
                                             float* __restrict__ biasacc) {
    __shared__ __align__(16) float Wcol[256][36];
    __shared__ __align__(16) float Ls[32][36];
    __shared__ __align__(16) float Tst[32][36];
    int jbb = blockIdx.x;      // 0..7
    int tid = threadIdx.x;
    int j0 = jbb * 32;

    {
        int r = tid >> 3, cq = (tid & 7) * 4;
        const float* row = &Lg[PAD(j0 + r) + j0];
        float4 v;
        v.x = (cq     <= r) ? row[cq]     : 0.f;
        v.y = (cq + 1 <= r) ? row[cq + 1] : 0.f;
        v.z = (cq + 2 <= r) ? row[cq + 2] : 0.f;
        v.w = (cq + 3 <= r) ? row[cq + 3] : 0.f;
        *(float4*)&Wcol[j0 + r][cq] = v;
    }
    __syncthreads();

    int r2 = (tid >> 4) * 2, c2 = (tid & 15) * 2;
    for (int ib = jbb + 1; ib < 8; ++ib) {
        int i0 = ib * 32;
        float t00 = 0, t01 = 0, t10 = 0, t11 = 0;
        for (int kb = jbb; kb < ib; ++kb) {
            __syncthreads();
            {
                int r = tid >> 3, cq = (tid & 7) * 4;
                *(float4*)&Ls[r][cq] = *(const float4*)&Lg[PAD(i0 + r) + kb * 32 + cq];
            }
            __syncthreads();
            int kw = kb * 32;
#pragma unroll 8
            for (int q = 0; q < 32; ++q) {
                float l0 = Ls[r2][q], l1 = Ls[r2 + 1][q];
                float w0 = Wcol[kw + q][c2], w1 = Wcol[kw + q][c2 + 1];
                t00 += l0 * w0; t01 += l0 * w1;
                t10 += l1 * w0; t11 += l1 * w1;
            }
        }
        __syncthreads();
        Tst[r2][c2] = t00;     Tst[r2][c2 + 1] = t01;
        Tst[r2 + 1][c2] = t10; Tst[r2 + 1][c2 + 1] = t11;
        {
            int r = tid >> 3, cq = (tid & 7) * 4;
            const float* row = &Lg[PAD(i0 + r) + i0];
            float4 v;
            v.x = (cq     <= r) ? row[cq]     : 0.f;
            v.y = (cq + 1 <= r) ? row[cq + 1] : 0.f;
            v.z = (cq + 2 <= r) ? row[cq + 2] : 0.f;
            v.w = (cq + 3 <= r) ? row[cq + 3] : 0.f;
            *(float4*)&Ls[r][cq] = v;
        }
        __syncthreads();
        float w00 = 0, w01 = 0, w10 = 0, w11 = 0;
#pragma unroll 8
        for (int q = 0; q < 32; ++q) {
            float d0 = Ls[r2][q], d1 = Ls[r2 + 1][q];
            float tq0 = Tst[q][c2], tq1 = Tst[q][c2 + 1];
            w00 += d0 * tq0; w01 += d0 * tq1;
            w10 += d1 * tq0; w11 += d1 * tq1;
        }
        Wcol[i0 + r2][c2] = -w00;     Wcol[i0 + r2][c2 + 1] = -w01;
        Wcol[i0 + r2 + 1][c2] = -w10; Wcol[i0 + r2 + 1][c2 + 1] = -w11;
    }
    __syncthreads();

    {
        int r = tid;
        if (r >= j0) {
            float s = 0.f;
#pragma unroll 8
            for (int c = 0; c < 32; ++c)
                s += Wcol[r][c] * sums[j0 + c];
            atomicAdd(&biasacc[r], s * (1.f / (float)NROWS));
        }
    }
    // Wg columns [j0,j0+32): gamma-fold + bf16 hi/lo split
    for (int u = tid; u < 2048; u += 256) {
        int r = u >> 3, cq = (u & 7) * 4;
        float w0 = 0.f, w1 = 0.f, w2 = 0.f, w3 = 0.f;
        if (r >= j0) {
            float g = gamma[r];
            w0 = Wcol[r][cq] * g;     w1 = Wcol[r][cq + 1] * g;
            w2 = Wcol[r][cq + 2] * g; w3 = Wcol[r][cq + 3] * g;
        }
        unsigned h01, l01, h23, l23;
        split2(w0, w1, h01, l01);
        split2(w2, w3, h23, l23);
        unsigned idx = (unsigned)(r * 256 + j0 + cq) >> 1;
        ((unsigned*)Wghi)[idx]     = h01;
        ((unsigned*)Wghi)[idx + 1] = h23;
        ((unsigned*)Wglo)[idx]     = l01;
        ((unsigned*)Wglo)[idx + 1] = l23;
    }
}

// ---------------- K4: out = x * Wg^T + bias via bf16-split MFMA ----------------
__global__ __launch_bounds__(256, 1) void k_apply(const float* __restrict__ x,
                                                  const unsigned short* __restrict__ Wghi,
                                                  const unsigned short* __restrict__ Wglo,
                                                  const float* __restrict__ beta,
                                                  const float* __restrict__ gamma,
                                                  const float* __restrict__ biasacc,
                                                  float* __restrict__ out) {
    int tid = threadIdx.x, wave = tid >> 6, lane = tid & 63;
    int m = lane & 15, kg = lane >> 4;
    size_t rbase = (size_t)blockIdx.x * 128 + wave * 32;   // this wave: 32 rows
    const float* xa = x + (rbase + m) * 256;
    const float* xb = x + (rbase + 16 + m) * 256;

    f32x4 acc[32];
#pragma unroll
    for (int t = 0; t < 32; ++t) acc[t] = 0.f;

#pragma unroll
    for (int kc = 0; kc < 8; ++kc) {
        int c0 = kc * 32 + kg * 8;
        bf16x8 ah0, al0, ah1, al1;
        split8(xa + c0, ah0, al0);
        split8(xb + c0, ah1, al1);
#pragma unroll
        for (int jt = 0; jt < 16; ++jt) {
            int wo = (jt * 16 + m) * 256 + c0;
            bf16x8 bh = *(const bf16x8*)&Wghi[wo];
            bf16x8 bl = *(const bf16x8*)&Wglo[wo];
            acc[jt] = MFMA16(ah0, bh, acc[jt], 0, 0, 0);
            acc[jt] = MFMA16(ah0, bl, acc[jt], 0, 0, 0);
            acc[jt] = MFMA16(al0, bh, acc[jt], 0, 0, 0);
            acc[16 + jt] = MFMA16(ah1, bh, acc[16 + jt], 0, 0, 0);
            acc[16 + jt] = MFMA16(ah1, bl, acc[16 + jt], 0, 0, 0);
            acc[16 + jt] = MFMA16(al1, bh, acc[16 + jt], 0, 0, 0);
        }
    }

#pragma unroll
    for (int jt = 0; jt < 16; ++jt) {
        int j = jt * 16 + m;
        float bb = beta[j] - gamma[j] * biasacc[j];
#pragma unroll
        for (int q = 0; q < 4; ++q) {
            out[(rbase + kg * 4 + q) * 256 + j]      = acc[jt][q] + bb;
            out[(rbase + 16 + kg * 4 + q) * 256 + j] = acc[16 + jt][q] + bb;
        }
    }
}

extern "C" void kernel_launch(void* const* d_in, const int* in_sizes, int n_in,
                              void* d_out, int out_size, void* d_ws, size_t ws_size,
                              hipStream_t stream) {
    const float* x     = (const float*)d_in[0];
    const float* gamma = (const float*)d_in[1];
    const float* beta  = (const float*)d_in[2];
    float* out  = (float*)d_out;
    float* ws   = (float*)d_ws;
    float* sums     = ws;                 // 256
    float* biasacc  = ws + 256;           // 256
    float* S8       = ws + 512;           // 8*65536
    float* Lg       = ws + 524800;        // 33280
    unsigned short* Wghi = (unsigned short*)(ws + 558080);   // 65536 bf16
    unsigned short* Wglo = (unsigned short*)(ws + 590848);   // 65536 bf16

    hipMemsetAsync(ws, 0, 524800 * sizeof(float), stream);
    hipLaunchKernelGGL(k_cov, dim3(224), dim3(256), 0, stream, x, S8, sums);
    hipLaunchKernelGGL(k_fact, dim3(1), dim3(512), 0, stream, S8, sums, Lg);
    hipLaunchKernelGGL(k_inv, dim3(8), dim3(256), 0, stream, Lg, sums, gamma, Wghi, Wglo, biasacc);
    hipLaunchKernelGGL(k_apply, dim3(1568), dim3(256), 0, stream, x, Wghi, Wglo, beta, gamma, biasacc, out);
}